// Round 1
// baseline (378.873 us; speedup 1.0000x reference)
//
#include <hip/hip_runtime.h>

// Problem constants (fixed inputs: ref_index=[0,1,2], current_ind=16)
// -> nsearch=1, dirates=[2], nref=3
// feats_r: (3,1,64,64,64) f32, feats_t: (1,64,64,64) f32,
// quantized_r: (3,1,1,256,256) i32
// out: (1,32,64,64) f32 then grid: (3,64,64,2) f32

#define NPIX 4096   // 64*64

__device__ __forceinline__ float dot64(const float4* __restrict__ a,
                                       const float4* __restrict__ b) {
  float s0 = 0.f, s1 = 0.f, s2 = 0.f, s3 = 0.f;
#pragma unroll
  for (int i = 0; i < 16; ++i) {
    float4 x = a[i];
    float4 y = b[i];
    s0 = fmaf(x.x, y.x, s0);
    s1 = fmaf(x.y, y.y, s1);
    s2 = fmaf(x.z, y.z, s2);
    s3 = fmaf(x.w, y.w, s3);
  }
  return (s0 + s1) + (s2 + s3);
}

// ---------------------------------------------------------------------------
// K0: transpose [c][pix] -> [pix][c] for feats_t and the 3 feats_r refs.
// blockIdx.y = img (0=t, 1..3=r), blockIdx.x = pixBase/64
__global__ __launch_bounds__(256) void k_transpose(
    const float* __restrict__ ft, const float* __restrict__ fr,
    float* __restrict__ tT, float* __restrict__ rT) {
  __shared__ float tile[64][65];
  int img = blockIdx.y;
  int pixBase = blockIdx.x * 64;
  const float* src = (img == 0) ? ft : fr + (img - 1) * (64 * NPIX);
  float* dst = (img == 0) ? tT : rT + (img - 1) * (64 * NPIX);
  int tid = threadIdx.x;
#pragma unroll
  for (int it = 0; it < 16; ++it) {
    int li = it * 256 + tid;
    int c = li >> 6, p = li & 63;
    tile[p][c] = src[c * NPIX + pixBase + p];
  }
  __syncthreads();
#pragma unroll
  for (int it = 0; it < 16; ++it) {
    int li = it * 256 + tid;
    int p = li >> 6, c = li & 63;
    dst[(pixBase + p) * 64 + c] = tile[p][c];
  }
}

// ---------------------------------------------------------------------------
// K1: 25x25 dilated (x2) correlation per pixel, softmax over 625,
// expectation -> offsets (x,y) scaled by dirate=2.
__global__ __launch_bounds__(256) void k_offsets(
    const float* __restrict__ tT, const float* __restrict__ rT0,
    float* __restrict__ off) {
  int pix = blockIdx.x;
  int y = pix >> 6, x = pix & 63;
  int tid = threadIdx.x;
  __shared__ __align__(16) float tv[64];
  __shared__ float rmax[4], rs[4], rsx[4], rsy[4];
  if (tid < 64) tv[tid] = tT[pix * 64 + tid];
  __syncthreads();
  const float4* tp = (const float4*)tv;

  float ccv[3];
  float lmax = -3e38f;
#pragma unroll
  for (int it = 0; it < 3; ++it) {
    int o = tid + it * 256;
    float v = -3e38f;
    if (o < 625) {
      int oy = o / 25, ox = o - oy * 25;
      int py = y + 2 * (oy - 12), px = x + 2 * (ox - 12);
      v = 0.f;  // zero-padded OOB correlation
      if ((unsigned)py < 64u && (unsigned)px < 64u)
        v = dot64(tp, (const float4*)&rT0[(py * 64 + px) * 64]);
    }
    ccv[it] = v;
    lmax = fmaxf(lmax, v);
  }
#pragma unroll
  for (int o = 32; o; o >>= 1) lmax = fmaxf(lmax, __shfl_down(lmax, o));
  if ((tid & 63) == 0) rmax[tid >> 6] = lmax;
  __syncthreads();
  float m = fmaxf(fmaxf(rmax[0], rmax[1]), fmaxf(rmax[2], rmax[3]));

  float s = 0.f, sx = 0.f, sy = 0.f;
#pragma unroll
  for (int it = 0; it < 3; ++it) {
    int o = tid + it * 256;
    int oy = o / 25, ox = o - oy * 25;
    float e = __expf(ccv[it] - m);  // inactive lanes: exp(-huge)=0
    s += e;
    sx += e * (float)(ox - 12);
    sy += e * (float)(oy - 12);
  }
#pragma unroll
  for (int o = 32; o; o >>= 1) {
    s += __shfl_down(s, o);
    sx += __shfl_down(sx, o);
    sy += __shfl_down(sy, o);
  }
  if ((tid & 63) == 0) {
    int w = tid >> 6;
    rs[w] = s; rsx[w] = sx; rsy[w] = sy;
  }
  __syncthreads();
  if (tid == 0) {
    float S = rs[0] + rs[1] + rs[2] + rs[3];
    float SX = rsx[0] + rsx[1] + rsx[2] + rsx[3];
    float SY = rsy[0] + rsy[1] + rsy[2] + rsy[3];
    off[pix * 2 + 0] = 2.f * SX / S;
    off[pix * 2 + 1] = 2.f * SY / S;
  }
}

// ---------------------------------------------------------------------------
// K2: per (ref k, pixel): 169 corr values (ref0 deformed-bilinear, refs 1-2
// shifted dots), gaussian*BETA softmax over 169 -> corr_ws; also grid (gx,gy).
__device__ __forceinline__ float cornerDot(const float4* tp,
                                           const float* __restrict__ r0,
                                           int yi, int xi, float w) {
  bool valid = ((unsigned)yi < 64u) & ((unsigned)xi < 64u);
  int yc = min(max(yi, 0), 63), xc = min(max(xi, 0), 63);
  float d = dot64(tp, (const float4*)&r0[(yc * 64 + xc) * 64]);
  return valid ? d * w : 0.f;
}

__global__ __launch_bounds__(256) void k_corr(
    const float* __restrict__ tT, const float* __restrict__ rT,
    const float* __restrict__ off, float* __restrict__ corrws,
    float* __restrict__ grid) {
  int pix = blockIdx.x;
  int k = blockIdx.y;
  int y = pix >> 6, x = pix & 63;
  int tid = threadIdx.x;
  __shared__ __align__(16) float tv[64];
  __shared__ float rmax[4], rs[4], rgx[4], rgy[4];
  if (tid < 64) tv[tid] = tT[pix * 64 + tid];
  __syncthreads();
  const float4* tp = (const float4*)tv;

  bool act = tid < 169;
  int n = tid;
  int i = n / 13, j = n - i * 13;

  float v = 0.f;
  if (k == 0) {
    float offx = off[pix * 2 + 0], offy = off[pix * 2 + 1];
    if (act) {
      float ys = (float)(y + i - 6) + offy;
      float xs = (float)(x + j - 6) + offx;
      float y0f = floorf(ys), x0f = floorf(xs);
      float wy = ys - y0f, wx = xs - x0f;
      int y0 = (int)y0f, x0 = (int)x0f;
      v  = cornerDot(tp, rT, y0,     x0,     (1.f - wy) * (1.f - wx));
      v += cornerDot(tp, rT, y0,     x0 + 1, (1.f - wy) * wx);
      v += cornerDot(tp, rT, y0 + 1, x0,     wy * (1.f - wx));
      v += cornerDot(tp, rT, y0 + 1, x0 + 1, wy * wx);
    }
  } else {
    int py = y + i - 6, px = x + j - 6;
    if (act && (unsigned)py < 64u && (unsigned)px < 64u)
      v = dot64(tp, (const float4*)&rT[(k * NPIX + py * 64 + px) * 64]);
  }

  float di = (float)((i - 6) * (i - 6) + (j - 6) * (j - 6));
  float sc = act ? 50.f * __expf(-0.5f * di) * v : -3e38f;

  float lmax = sc;
#pragma unroll
  for (int o = 32; o; o >>= 1) lmax = fmaxf(lmax, __shfl_down(lmax, o));
  if ((tid & 63) == 0) rmax[tid >> 6] = lmax;
  __syncthreads();
  float m = fmaxf(fmaxf(rmax[0], rmax[1]), fmaxf(rmax[2], rmax[3]));

  float e = __expf(sc - m);  // inactive: 0
  int yy = y + i - 6, xx = x + j - 6;
  bool inb = act && (unsigned)yy < 64u && (unsigned)xx < 64u;
  float xgv = inb ? (-1.f + (2.f / 63.f) * (float)xx) : 0.f;
  float ygv = inb ? (-1.f + (2.f / 63.f) * (float)yy) : 0.f;
  float s = e, gx = e * xgv, gy = e * ygv;
#pragma unroll
  for (int o = 32; o; o >>= 1) {
    s += __shfl_down(s, o);
    gx += __shfl_down(gx, o);
    gy += __shfl_down(gy, o);
  }
  if ((tid & 63) == 0) {
    int w = tid >> 6;
    rs[w] = s; rgx[w] = gx; rgy[w] = gy;
  }
  __syncthreads();
  float S = rs[0] + rs[1] + rs[2] + rs[3];
  if (act) corrws[(k * NPIX + pix) * 169 + n] = e / S;
  if (tid == 0) {
    float GX = rgx[0] + rgx[1] + rgx[2] + rgx[3];
    float GY = rgy[0] + rgy[1] + rgy[2] + rgy[3];
    grid[(k * NPIX + pix) * 2 + 0] = GX / S;
    grid[(k * NPIX + pix) * 2 + 1] = GY / S;
  }
}

// ---------------------------------------------------------------------------
// K3: out[c,pix] = sum over refs/taps of corr * onehot(label). Lane = channel
// (lanes 0..31 -> pixel A, 32..63 -> pixel B), accumulate via cndmask.
__device__ __forceinline__ float cornerLbl(const int* __restrict__ q0, int yi,
                                           int xi, float w, int c) {
  bool valid = ((unsigned)yi < 64u) & ((unsigned)xi < 64u);
  int yc = min(max(yi, 0), 63), xc = min(max(xi, 0), 63);
  int lbl = q0[yc * 1024 + xc * 4];  // quantized_r[k,0,0,4y,4x]
  return (valid && lbl == c) ? w : 0.f;
}

__global__ __launch_bounds__(256) void k_out(
    const float* __restrict__ corrws, const float* __restrict__ off,
    const int* __restrict__ q, float* __restrict__ out) {
  int tid = threadIdx.x;
  int wave = tid >> 6, lane = tid & 63, half = lane >> 5, c = lane & 31;
  int pix = blockIdx.x * 8 + wave * 2 + half;
  int y = pix >> 6, x = pix & 63;
  float acc = 0.f;

  // ref 0: deformed bilinear one-hot gather
  {
    float offx = off[pix * 2 + 0], offy = off[pix * 2 + 1];
    const float* cr = corrws + pix * 169;
    const int* q0 = q;
    int n = 0;
#pragma unroll 1
    for (int i = 0; i < 13; ++i) {
#pragma unroll 1
      for (int j = 0; j < 13; ++j, ++n) {
        float p = cr[n];
        float ys = (float)(y + i - 6) + offy;
        float xs = (float)(x + j - 6) + offx;
        float y0f = floorf(ys), x0f = floorf(xs);
        float wy = ys - y0f, wx = xs - x0f;
        int y0 = (int)y0f, x0 = (int)x0f;
        acc += cornerLbl(q0, y0,     x0,     (1.f - wy) * (1.f - wx) * p, c);
        acc += cornerLbl(q0, y0,     x0 + 1, (1.f - wy) * wx * p, c);
        acc += cornerLbl(q0, y0 + 1, x0,     wy * (1.f - wx) * p, c);
        acc += cornerLbl(q0, y0 + 1, x0 + 1, wy * wx * p, c);
      }
    }
  }

  // refs 1,2: integer-shift one-hot gather
  for (int k = 1; k < 3; ++k) {
    const float* cr = corrws + (k * NPIX + pix) * 169;
    const int* qk = q + k * 65536;
    int n = 0;
#pragma unroll 1
    for (int i = 0; i < 13; ++i) {
      int yy = y + i - 6;
#pragma unroll 1
      for (int j = 0; j < 13; ++j, ++n) {
        int xx = x + j - 6;
        if ((unsigned)yy < 64u && (unsigned)xx < 64u) {
          int lbl = qk[yy * 1024 + xx * 4];
          acc += (lbl == c) ? cr[n] : 0.f;
        }
      }
    }
  }

  out[c * NPIX + pix] = acc;
}

// ---------------------------------------------------------------------------
extern "C" void kernel_launch(void* const* d_in, const int* in_sizes, int n_in,
                              void* d_out, int out_size, void* d_ws,
                              size_t ws_size, hipStream_t stream) {
  const float* fr = (const float*)d_in[0];  // feats_r (3,1,64,64,64)
  const float* ft = (const float*)d_in[1];  // feats_t (1,64,64,64)
  const int* q = (const int*)d_in[2];       // quantized_r (3,1,1,256,256)
  float* out = (float*)d_out;               // 131072 + 24576 floats
  float* grid = out + 32 * NPIX;

  float* ws = (float*)d_ws;
  float* tT = ws;                  // 4096*64
  float* rT = ws + 262144;         // 3*4096*64
  float* off = ws + 1048576;       // 4096*2
  float* corrws = ws + 1056768;    // 3*4096*169

  k_transpose<<<dim3(64, 4), 256, 0, stream>>>(ft, fr, tT, rT);
  k_offsets<<<NPIX, 256, 0, stream>>>(tT, rT, off);
  k_corr<<<dim3(NPIX, 3), 256, 0, stream>>>(tT, rT, off, corrws, grid);
  k_out<<<512, 256, 0, stream>>>(corrws, off, q, out);
}

// Round 2
// 79.475 us; speedup vs baseline: 4.7672x; 4.7672x over previous
//
#include <hip/hip_runtime.h>

// Problem constants (fixed inputs: ref_index=[0,1,2], current_ind=16)
// -> nsearch=1, dirates=[2], nref=3
// feats_r: (3,1,64,64,64) f32, feats_t: (1,64,64,64) f32,
// quantized_r: (3,1,1,256,256) i32
// out: (1,32,64,64) f32 then grid: (3,64,64,2) f32

#define NPIX 4096   // 64*64

// 4-lane cooperative dot over 64 channels: lane tx of a 4-lane group reads
// float4 chunks {tx, tx+4, tx+8, tx+12} (lanes 0-3 hit the same 64B line per
// chunk round -> 16 lines per wave instr instead of 64). Result in all 4 lanes.
__device__ __forceinline__ float qdot(float4 ta, float4 tb, float4 tc,
                                      float4 td,
                                      const float* __restrict__ rbase,
                                      int tx) {
  const float4* r = (const float4*)rbase;
  float4 a = r[tx], b = r[tx + 4], c = r[tx + 8], d = r[tx + 12];
  float s0 = 0.f, s1 = 0.f, s2 = 0.f, s3 = 0.f;
  s0 = fmaf(ta.x, a.x, s0); s1 = fmaf(ta.y, a.y, s1);
  s2 = fmaf(ta.z, a.z, s2); s3 = fmaf(ta.w, a.w, s3);
  s0 = fmaf(tb.x, b.x, s0); s1 = fmaf(tb.y, b.y, s1);
  s2 = fmaf(tb.z, b.z, s2); s3 = fmaf(tb.w, b.w, s3);
  s0 = fmaf(tc.x, c.x, s0); s1 = fmaf(tc.y, c.y, s1);
  s2 = fmaf(tc.z, c.z, s2); s3 = fmaf(tc.w, c.w, s3);
  s0 = fmaf(td.x, d.x, s0); s1 = fmaf(td.y, d.y, s1);
  s2 = fmaf(td.z, d.z, s2); s3 = fmaf(td.w, d.w, s3);
  float v = (s0 + s1) + (s2 + s3);
  v += __shfl_xor(v, 1);
  v += __shfl_xor(v, 2);
  return v;
}

// Shared softmax tail for the 169-tap gaussian-weighted softmax + grid.
__device__ __forceinline__ void smax_tail(float v, int tid, int y, int x,
                                          float* __restrict__ corrp,
                                          float* __restrict__ gridp,
                                          float* rmax, float* rs, float* rgx,
                                          float* rgy) {
  bool act = tid < 169;
  int i = tid / 13, j = tid - i * 13;
  float di = (float)((i - 6) * (i - 6) + (j - 6) * (j - 6));
  float sc = act ? 50.f * __expf(-0.5f * di) * v : -3e38f;
  float lmax = sc;
#pragma unroll
  for (int o = 32; o; o >>= 1) lmax = fmaxf(lmax, __shfl_down(lmax, o));
  if ((tid & 63) == 0) rmax[tid >> 6] = lmax;
  __syncthreads();
  float m = fmaxf(fmaxf(rmax[0], rmax[1]), fmaxf(rmax[2], rmax[3]));
  float e = __expf(sc - m);  // inactive: 0
  int yy = y + i - 6, xx = x + j - 6;
  bool inb = act && (unsigned)yy < 64u && (unsigned)xx < 64u;
  float xgv = inb ? (-1.f + (2.f / 63.f) * (float)xx) : 0.f;
  float ygv = inb ? (-1.f + (2.f / 63.f) * (float)yy) : 0.f;
  float s = e, gx = e * xgv, gy = e * ygv;
#pragma unroll
  for (int o = 32; o; o >>= 1) {
    s += __shfl_down(s, o);
    gx += __shfl_down(gx, o);
    gy += __shfl_down(gy, o);
  }
  if ((tid & 63) == 0) {
    int w = tid >> 6;
    rs[w] = s; rgx[w] = gx; rgy[w] = gy;
  }
  __syncthreads();
  float S = rs[0] + rs[1] + rs[2] + rs[3];
  if (act) corrp[tid] = e / S;
  if (tid == 0) {
    gridp[0] = (rgx[0] + rgx[1] + rgx[2] + rgx[3]) / S;
    gridp[1] = (rgy[0] + rgy[1] + rgy[2] + rgy[3]) / S;
  }
}

// ---------------------------------------------------------------------------
// K0: transpose [c][pix] -> [pix][c] for feats_t and the 3 feats_r refs.
__global__ __launch_bounds__(256) void k_transpose(
    const float* __restrict__ ft, const float* __restrict__ fr,
    float* __restrict__ tT, float* __restrict__ rT) {
  __shared__ float tile[64][65];
  int img = blockIdx.y;
  int pixBase = blockIdx.x * 64;
  const float* src = (img == 0) ? ft : fr + (img - 1) * (64 * NPIX);
  float* dst = (img == 0) ? tT : rT + (img - 1) * (64 * NPIX);
  int tid = threadIdx.x;
#pragma unroll
  for (int it = 0; it < 16; ++it) {
    int li = it * 256 + tid;
    int c = li >> 6, p = li & 63;
    tile[p][c] = src[c * NPIX + pixBase + p];
  }
  __syncthreads();
#pragma unroll
  for (int it = 0; it < 16; ++it) {
    int li = it * 256 + tid;
    int p = li >> 6, c = li & 63;
    dst[(pixBase + p) * 64 + c] = tile[p][c];
  }
}

// ---------------------------------------------------------------------------
// K1: 25x25 dilated (x2) correlation per pixel -> LDS -> softmax-expectation
// -> offsets. One block per pixel; 64 4-lane groups compute the 625 dots.
__global__ __launch_bounds__(256) void k_off(const float* __restrict__ tT,
                                             const float* __restrict__ rT0,
                                             float* __restrict__ off) {
  int pix = blockIdx.x;
  int y = pix >> 6, x = pix & 63;
  int tid = threadIdx.x;
  int g = tid >> 2, tx = tid & 3;
  __shared__ __align__(16) float tv[64];
  __shared__ float cc[625];
  __shared__ float rmax[4], rs[4], rsx[4], rsy[4];
  if (tid < 64) tv[tid] = tT[pix * 64 + tid];
  __syncthreads();
  const float4* tvp = (const float4*)tv;
  float4 ta = tvp[tx], tb = tvp[tx + 4], tc = tvp[tx + 8], td = tvp[tx + 12];

  for (int r = 0; r < 10; ++r) {
    int tap = g + r * 64;
    if (tap < 625) {
      int oy = tap / 25, ox = tap - oy * 25;
      int ry = y + 2 * (oy - 12), rx = x + 2 * (ox - 12);
      float v = 0.f;
      if ((unsigned)ry < 64u && (unsigned)rx < 64u)
        v = qdot(ta, tb, tc, td, &rT0[(ry * 64 + rx) * 64], tx);
      if (tx == 0) cc[tap] = v;
    }
  }
  __syncthreads();

  float vv[3];
  float lmax = -3e38f;
#pragma unroll
  for (int it = 0; it < 3; ++it) {
    int o = tid + it * 256;
    float v = (o < 625) ? cc[o] : -3e38f;
    vv[it] = v;
    lmax = fmaxf(lmax, v);
  }
#pragma unroll
  for (int o = 32; o; o >>= 1) lmax = fmaxf(lmax, __shfl_down(lmax, o));
  if ((tid & 63) == 0) rmax[tid >> 6] = lmax;
  __syncthreads();
  float m = fmaxf(fmaxf(rmax[0], rmax[1]), fmaxf(rmax[2], rmax[3]));

  float s = 0.f, sx = 0.f, sy = 0.f;
#pragma unroll
  for (int it = 0; it < 3; ++it) {
    int o = tid + it * 256;
    int oy = o / 25, ox = o - oy * 25;
    float e = __expf(vv[it] - m);  // inactive lanes: 0
    s += e;
    sx += e * (float)(ox - 12);
    sy += e * (float)(oy - 12);
  }
#pragma unroll
  for (int o = 32; o; o >>= 1) {
    s += __shfl_down(s, o);
    sx += __shfl_down(sx, o);
    sy += __shfl_down(sy, o);
  }
  if ((tid & 63) == 0) {
    int w = tid >> 6;
    rs[w] = s; rsx[w] = sx; rsy[w] = sy;
  }
  __syncthreads();
  if (tid == 0) {
    float S = rs[0] + rs[1] + rs[2] + rs[3];
    float SX = rsx[0] + rsx[1] + rsx[2] + rsx[3];
    float SY = rsy[0] + rsy[1] + rsy[2] + rsy[3];
    off[pix * 2 + 0] = 2.f * SX / S;
    off[pix * 2 + 1] = 2.f * SY / S;
  }
}

// ---------------------------------------------------------------------------
// K2a: ref0 deformed corr. Bilinear weights are per-pixel constants, so the
// 169 taps x 4 corners collapse onto a 14x14 integer dot grid (196 dots).
__global__ __launch_bounds__(256) void k_corr0(
    const float* __restrict__ tT, const float* __restrict__ rT0,
    const float* __restrict__ off, float* __restrict__ corrws,
    float* __restrict__ grid) {
  int pix = blockIdx.x;
  int y = pix >> 6, x = pix & 63;
  int tid = threadIdx.x;
  int g = tid >> 2, tx = tid & 3;
  __shared__ __align__(16) float tv[64];
  __shared__ float D[196];
  __shared__ float rmax[4], rs[4], rgx[4], rgy[4];
  float offx = off[pix * 2 + 0], offy = off[pix * 2 + 1];
  float fy = floorf(offy), fx = floorf(offx);
  float wy = offy - fy, wx = offx - fx;
  int iy0 = y + (int)fy, ix0 = x + (int)fx;
  if (tid < 64) tv[tid] = tT[pix * 64 + tid];
  __syncthreads();
  const float4* tvp = (const float4*)tv;
  float4 ta = tvp[tx], tb = tvp[tx + 4], tc = tvp[tx + 8], td = tvp[tx + 12];

  for (int r = 0; r < 4; ++r) {
    int idx = g + r * 64;
    if (idx < 196) {
      int a = idx / 14, b = idx - a * 14;
      int ry = iy0 - 6 + a, rx = ix0 - 6 + b;
      float v = 0.f;
      if ((unsigned)ry < 64u && (unsigned)rx < 64u)
        v = qdot(ta, tb, tc, td, &rT0[(ry * 64 + rx) * 64], tx);
      if (tx == 0) D[idx] = v;
    }
  }
  __syncthreads();

  float v = 0.f;
  if (tid < 169) {
    int i = tid / 13, j = tid - i * 13;
    float w00 = (1.f - wy) * (1.f - wx), w01 = (1.f - wy) * wx;
    float w10 = wy * (1.f - wx), w11 = wy * wx;
    v = w00 * D[i * 14 + j] + w01 * D[i * 14 + j + 1] +
        w10 * D[(i + 1) * 14 + j] + w11 * D[(i + 1) * 14 + j + 1];
  }
  smax_tail(v, tid, y, x, corrws + pix * 169, grid + pix * 2, rmax, rs, rgx,
            rgy);
}

// ---------------------------------------------------------------------------
// K2b: refs 1,2 plain 13x13 corr + gaussian softmax, fused.
__global__ __launch_bounds__(256) void k_corrk(
    const float* __restrict__ tT, const float* __restrict__ rT,
    float* __restrict__ corrws, float* __restrict__ grid) {
  int pix = blockIdx.x;
  int k = blockIdx.y + 1;
  int y = pix >> 6, x = pix & 63;
  int tid = threadIdx.x;
  int g = tid >> 2, tx = tid & 3;
  __shared__ __align__(16) float tv[64];
  __shared__ float cc[169];
  __shared__ float rmax[4], rs[4], rgx[4], rgy[4];
  if (tid < 64) tv[tid] = tT[pix * 64 + tid];
  __syncthreads();
  const float4* tvp = (const float4*)tv;
  float4 ta = tvp[tx], tb = tvp[tx + 4], tc = tvp[tx + 8], td = tvp[tx + 12];
  const float* rbase = rT + k * (64 * NPIX);

  for (int r = 0; r < 3; ++r) {
    int tap = g + r * 64;
    if (tap < 169) {
      int i = tap / 13, j = tap - i * 13;
      int ry = y + i - 6, rx = x + j - 6;
      float v = 0.f;
      if ((unsigned)ry < 64u && (unsigned)rx < 64u)
        v = qdot(ta, tb, tc, td, &rbase[(ry * 64 + rx) * 64], tx);
      if (tx == 0) cc[tap] = v;
    }
  }
  __syncthreads();
  float v = (tid < 169) ? cc[tid] : 0.f;
  smax_tail(v, tid, y, x, corrws + (k * NPIX + pix) * 169,
            grid + (k * NPIX + pix) * 2, rmax, rs, rgx, rgy);
}

// ---------------------------------------------------------------------------
// K3: out[c,pix] via per-pixel 32-bin LDS histogram. Ref0 uses the inverse
// bilinear factorization: each of the 196 grid positions gets one label load
// and one atomicAdd with the 4-tap-combined weight.
__global__ __launch_bounds__(256) void k_out(const float* __restrict__ corrws,
                                             const float* __restrict__ off,
                                             const int* __restrict__ q,
                                             float* __restrict__ out) {
  int tid = threadIdx.x;
  int pix0 = blockIdx.x * 8;
  __shared__ float bins[8][32];
  __shared__ float cr[8][169];
  __shared__ float offs[8][2];
  bins[tid >> 5][tid & 31] = 0.f;
  if (tid < 16) offs[tid >> 1][tid & 1] = off[(pix0 + (tid >> 1)) * 2 + (tid & 1)];
  for (int i = tid; i < 8 * 169; i += 256) {
    int g = i / 169, n = i - g * 169;
    cr[g][n] = corrws[(pix0 + g) * 169 + n];
  }
  __syncthreads();

  // ref0: 8 pixels x 196 grid positions
  for (int s = tid; s < 8 * 196; s += 256) {
    int g = s / 196, m = s - g * 196;
    int a = m / 14, b = m - a * 14;
    int pix = pix0 + g, y = pix >> 6, x = pix & 63;
    float offx = offs[g][0], offy = offs[g][1];
    float fy = floorf(offy), fx = floorf(offx);
    float wy = offy - fy, wx = offx - fx;
    int ry = y + (int)fy - 6 + a, rx = x + (int)fx - 6 + b;
    if ((unsigned)ry < 64u && (unsigned)rx < 64u) {
      float w00 = (1.f - wy) * (1.f - wx), w01 = (1.f - wy) * wx;
      float w10 = wy * (1.f - wx), w11 = wy * wx;
      float wgt = 0.f;
      if (a < 13) {
        if (b < 13) wgt = fmaf(w00, cr[g][a * 13 + b], wgt);
        if (b > 0) wgt = fmaf(w01, cr[g][a * 13 + b - 1], wgt);
      }
      if (a > 0) {
        if (b < 13) wgt = fmaf(w10, cr[g][(a - 1) * 13 + b], wgt);
        if (b > 0) wgt = fmaf(w11, cr[g][(a - 1) * 13 + b - 1], wgt);
      }
      if (wgt != 0.f) {
        int lbl = q[ry * 1024 + rx * 4];
        atomicAdd(&bins[g][lbl], wgt);
      }
    }
  }

  // refs 1,2: integer taps
  for (int k = 1; k < 3; ++k) {
    __syncthreads();
    for (int i = tid; i < 8 * 169; i += 256) {
      int g = i / 169, n = i - g * 169;
      cr[g][n] = corrws[((k << 12) + pix0 + g) * 169 + n];
    }
    __syncthreads();
    for (int s = tid; s < 8 * 169; s += 256) {
      int g = s / 169, n = s - g * 169;
      int i2 = n / 13, j2 = n - i2 * 13;
      int pix = pix0 + g, y = pix >> 6, x = pix & 63;
      int yy = y + i2 - 6, xx = x + j2 - 6;
      if ((unsigned)yy < 64u && (unsigned)xx < 64u) {
        int lbl = q[k * 65536 + yy * 1024 + xx * 4];
        atomicAdd(&bins[g][lbl], cr[g][n]);
      }
    }
  }
  __syncthreads();
  out[(tid >> 3) * NPIX + pix0 + (tid & 7)] = bins[tid & 7][tid >> 3];
}

// ---------------------------------------------------------------------------
extern "C" void kernel_launch(void* const* d_in, const int* in_sizes, int n_in,
                              void* d_out, int out_size, void* d_ws,
                              size_t ws_size, hipStream_t stream) {
  const float* fr = (const float*)d_in[0];  // feats_r (3,1,64,64,64)
  const float* ft = (const float*)d_in[1];  // feats_t (1,64,64,64)
  const int* q = (const int*)d_in[2];       // quantized_r (3,1,1,256,256)
  float* out = (float*)d_out;               // 131072 + 24576 floats
  float* grid = out + 32 * NPIX;

  float* ws = (float*)d_ws;
  float* tT = ws;                  // 4096*64
  float* rT = ws + 262144;         // 3*4096*64
  float* off = ws + 1048576;       // 4096*2
  float* corrws = ws + 1056768;    // 3*4096*169

  k_transpose<<<dim3(64, 4), 256, 0, stream>>>(ft, fr, tT, rT);
  k_off<<<NPIX, 256, 0, stream>>>(tT, rT, off);
  k_corr0<<<NPIX, 256, 0, stream>>>(tT, rT, off, corrws, grid);
  k_corrk<<<dim3(NPIX, 2), 256, 0, stream>>>(tT, rT, corrws, grid);
  k_out<<<512, 256, 0, stream>>>(corrws, off, q, out);
}

// Round 3
// 68.064 us; speedup vs baseline: 5.5664x; 1.1676x over previous
//
#include <hip/hip_runtime.h>

// Problem constants (fixed inputs: ref_index=[0,1,2], current_ind=16)
// -> nsearch=1, dirates=[2], nref=3
// feats_r: (3,1,64,64,64) f32, feats_t: (1,64,64,64) f32,
// quantized_r: (3,1,1,256,256) i32
// out: (1,32,64,64) f32 then grid: (3,64,64,2) f32

#define NPIX 4096   // 64*64

// 16-channel partial dot (this lane's quarter of the 64-ch dot).
__device__ __forceinline__ float pdot(float4 t0, float4 t1, float4 t2,
                                      float4 t3, float4 a, float4 b, float4 c,
                                      float4 d) {
  float s0 = 0.f, s1 = 0.f, s2 = 0.f, s3 = 0.f;
  s0 = fmaf(t0.x, a.x, s0); s1 = fmaf(t0.y, a.y, s1);
  s2 = fmaf(t0.z, a.z, s2); s3 = fmaf(t0.w, a.w, s3);
  s0 = fmaf(t1.x, b.x, s0); s1 = fmaf(t1.y, b.y, s1);
  s2 = fmaf(t1.z, b.z, s2); s3 = fmaf(t1.w, b.w, s3);
  s0 = fmaf(t2.x, c.x, s0); s1 = fmaf(t2.y, c.y, s1);
  s2 = fmaf(t2.z, c.z, s2); s3 = fmaf(t2.w, c.w, s3);
  s0 = fmaf(t3.x, d.x, s0); s1 = fmaf(t3.y, d.y, s1);
  s2 = fmaf(t3.z, d.z, s2); s3 = fmaf(t3.w, d.w, s3);
  return (s0 + s1) + (s2 + s3);
}

// 4-lane cooperative dot (all lanes get result): used by k_corr0.
__device__ __forceinline__ float qdot(float4 ta, float4 tb, float4 tc,
                                      float4 td,
                                      const float* __restrict__ rbase,
                                      int tx) {
  const float4* r = (const float4*)rbase;
  float v = pdot(ta, tb, tc, td, r[tx], r[tx + 4], r[tx + 8], r[tx + 12]);
  v += __shfl_xor(v, 1);
  v += __shfl_xor(v, 2);
  return v;
}

// 4-lane transpose-reduce: input p0..p3 = this lane's 16-ch partials for
// pixels 0..3; output: lane tx holds the full 64-ch dot of pixel tx.
__device__ __forceinline__ float xpose_reduce4(float p0, float p1, float p2,
                                               float p3, int tx) {
  bool o1 = tx & 1, o2 = tx & 2;
  float x01 = __shfl_xor(o1 ? p0 : p1, 1);
  float x23 = __shfl_xor(o1 ? p2 : p3, 1);
  float sA = (o1 ? p1 : p0) + x01;  // s_{tx&1} over lane pair
  float sB = (o1 ? p3 : p2) + x23;  // s_{2+(tx&1)} over lane pair
  float z = __shfl_xor(o2 ? sA : sB, 2);
  return o2 ? (sB + z) : (sA + z);
}

// ---------------------------------------------------------------------------
// K0: transpose [c][pix] -> [pix][c] for feats_t and the 3 feats_r refs.
__global__ __launch_bounds__(256) void k_transpose(
    const float* __restrict__ ft, const float* __restrict__ fr,
    float* __restrict__ tT, float* __restrict__ rT) {
  __shared__ float tile[64][65];
  int img = blockIdx.y;
  int pixBase = blockIdx.x * 64;
  const float* src = (img == 0) ? ft : fr + (img - 1) * (64 * NPIX);
  float* dst = (img == 0) ? tT : rT + (img - 1) * (64 * NPIX);
  int tid = threadIdx.x;
#pragma unroll
  for (int it = 0; it < 16; ++it) {
    int li = it * 256 + tid;
    int c = li >> 6, p = li & 63;
    tile[p][c] = src[c * NPIX + pixBase + p];
  }
  __syncthreads();
#pragma unroll
  for (int it = 0; it < 16; ++it) {
    int li = it * 256 + tid;
    int p = li >> 6, c = li & 63;
    dst[(pixBase + p) * 64 + c] = tile[p][c];
  }
}

// ---------------------------------------------------------------------------
// K1: offsets. Block = 4 same-parity pixels {x0, x0+2, x0+4, x0+6} of row y.
// Union tap grid 25 rows x 28 cols = 700 r-positions (vs 4x625): each loaded
// r-vector feeds 4 dots. Then one wave per pixel does softmax-expectation.
__global__ __launch_bounds__(256) void k_off4(const float* __restrict__ tT,
                                              const float* __restrict__ rT0,
                                              float* __restrict__ off) {
  int xg = blockIdx.x, y = blockIdx.y;
  int x0 = (xg >> 1) * 8 + (xg & 1);  // pixels x0 + {0,2,4,6}
  int tid = threadIdx.x;
  int g = tid >> 2, tx = tid & 3;
  __shared__ float cc[4][625];
  for (int i = tid; i < 2500; i += 256) ((float*)&cc[0][0])[i] = 0.f;

  // t fragments: 4 pixels x 16 ch (4 float4) per lane
  const float4* tp0 = (const float4*)&tT[(y * 64 + x0 + 0) * 64];
  const float4* tp1 = (const float4*)&tT[(y * 64 + x0 + 2) * 64];
  const float4* tp2 = (const float4*)&tT[(y * 64 + x0 + 4) * 64];
  const float4* tp3 = (const float4*)&tT[(y * 64 + x0 + 6) * 64];
  float4 t00 = tp0[tx], t01 = tp0[tx + 4], t02 = tp0[tx + 8], t03 = tp0[tx + 12];
  float4 t10 = tp1[tx], t11 = tp1[tx + 4], t12 = tp1[tx + 8], t13 = tp1[tx + 12];
  float4 t20 = tp2[tx], t21 = tp2[tx + 4], t22 = tp2[tx + 8], t23 = tp2[tx + 12];
  float4 t30 = tp3[tx], t31 = tp3[tx + 4], t32 = tp3[tx + 8], t33 = tp3[tx + 12];
  __syncthreads();  // cc zero-init visible to all waves

#pragma unroll 1
  for (int r = 0; r < 11; ++r) {
    int tu = g + r * 64;
    if (tu < 700) {
      int oy = tu / 28, u = tu - oy * 28;
      int ry = y + 2 * (oy - 12);
      int rx = x0 - 24 + 2 * u;
      if ((unsigned)ry < 64u && (unsigned)rx < 64u) {
        const float4* rp = (const float4*)&rT0[(ry * 64 + rx) * 64];
        float4 ra = rp[tx], rb = rp[tx + 4], rc = rp[tx + 8], rd = rp[tx + 12];
        float p0 = pdot(t00, t01, t02, t03, ra, rb, rc, rd);
        float p1 = pdot(t10, t11, t12, t13, ra, rb, rc, rd);
        float p2 = pdot(t20, t21, t22, t23, ra, rb, rc, rd);
        float p3 = pdot(t30, t31, t32, t33, ra, rb, rc, rd);
        float v = xpose_reduce4(p0, p1, p2, p3, tx);
        int ox = u - tx;  // lane tx owns pixel tx
        if ((unsigned)ox < 25u) cc[tx][oy * 25 + ox] = v;
      }
    }
  }
  __syncthreads();

  // one wave per pixel: softmax expectation over 625 taps
  int w = tid >> 6, lane = tid & 63;
  float vv[10];
  float lmax = -3e38f;
#pragma unroll
  for (int it = 0; it < 10; ++it) {
    int o = lane + it * 64;
    float v = (o < 625) ? cc[w][o] : -3e38f;
    vv[it] = v;
    lmax = fmaxf(lmax, v);
  }
#pragma unroll
  for (int o = 32; o; o >>= 1) lmax = fmaxf(lmax, __shfl_down(lmax, o));
  float m = __shfl(lmax, 0);
  float s = 0.f, sx = 0.f, sy = 0.f;
#pragma unroll
  for (int it = 0; it < 10; ++it) {
    int o = lane + it * 64;
    int oy = o / 25, ox = o - oy * 25;
    float e = __expf(vv[it] - m);  // padding lanes: 0
    s += e;
    sx += e * (float)(ox - 12);
    sy += e * (float)(oy - 12);
  }
#pragma unroll
  for (int o = 32; o; o >>= 1) {
    s += __shfl_down(s, o);
    sx += __shfl_down(sx, o);
    sy += __shfl_down(sy, o);
  }
  if (lane == 0) {
    int pix = y * 64 + x0 + 2 * w;
    off[pix * 2 + 0] = 2.f * sx / s;
    off[pix * 2 + 1] = 2.f * sy / s;
  }
}

// ---------------------------------------------------------------------------
// K2a: ref0 deformed corr. Bilinear weights are per-pixel constants, so the
// 169 taps x 4 corners collapse onto a 14x14 integer dot grid (196 dots).
__global__ __launch_bounds__(256) void k_corr0(
    const float* __restrict__ tT, const float* __restrict__ rT0,
    const float* __restrict__ off, float* __restrict__ corrws,
    float* __restrict__ grid) {
  int pix = blockIdx.x;
  int y = pix >> 6, x = pix & 63;
  int tid = threadIdx.x;
  int g = tid >> 2, tx = tid & 3;
  __shared__ __align__(16) float tv[64];
  __shared__ float D[196];
  __shared__ float rmax[4], rs[4], rgx[4], rgy[4];
  float offx = off[pix * 2 + 0], offy = off[pix * 2 + 1];
  float fy = floorf(offy), fx = floorf(offx);
  float wy = offy - fy, wx = offx - fx;
  int iy0 = y + (int)fy, ix0 = x + (int)fx;
  if (tid < 64) tv[tid] = tT[pix * 64 + tid];
  __syncthreads();
  const float4* tvp = (const float4*)tv;
  float4 ta = tvp[tx], tb = tvp[tx + 4], tc = tvp[tx + 8], td = tvp[tx + 12];

  for (int r = 0; r < 4; ++r) {
    int idx = g + r * 64;
    if (idx < 196) {
      int a = idx / 14, b = idx - a * 14;
      int ry = iy0 - 6 + a, rx = ix0 - 6 + b;
      float v = 0.f;
      if ((unsigned)ry < 64u && (unsigned)rx < 64u)
        v = qdot(ta, tb, tc, td, &rT0[(ry * 64 + rx) * 64], tx);
      if (tx == 0) D[idx] = v;
    }
  }
  __syncthreads();

  // softmax tail (169 taps across 256 threads)
  bool act = tid < 169;
  int i = tid / 13, j = tid - i * 13;
  float v = 0.f;
  if (act) {
    float w00 = (1.f - wy) * (1.f - wx), w01 = (1.f - wy) * wx;
    float w10 = wy * (1.f - wx), w11 = wy * wx;
    v = w00 * D[i * 14 + j] + w01 * D[i * 14 + j + 1] +
        w10 * D[(i + 1) * 14 + j] + w11 * D[(i + 1) * 14 + j + 1];
  }
  float di = (float)((i - 6) * (i - 6) + (j - 6) * (j - 6));
  float sc = act ? 50.f * __expf(-0.5f * di) * v : -3e38f;
  float lmax = sc;
#pragma unroll
  for (int o = 32; o; o >>= 1) lmax = fmaxf(lmax, __shfl_down(lmax, o));
  if ((tid & 63) == 0) rmax[tid >> 6] = lmax;
  __syncthreads();
  float m = fmaxf(fmaxf(rmax[0], rmax[1]), fmaxf(rmax[2], rmax[3]));
  float e = __expf(sc - m);
  int yy = y + i - 6, xx = x + j - 6;
  bool inb = act && (unsigned)yy < 64u && (unsigned)xx < 64u;
  float xgv = inb ? (-1.f + (2.f / 63.f) * (float)xx) : 0.f;
  float ygv = inb ? (-1.f + (2.f / 63.f) * (float)yy) : 0.f;
  float s = e, gx = e * xgv, gy = e * ygv;
#pragma unroll
  for (int o = 32; o; o >>= 1) {
    s += __shfl_down(s, o);
    gx += __shfl_down(gx, o);
    gy += __shfl_down(gy, o);
  }
  if ((tid & 63) == 0) {
    int wv = tid >> 6;
    rs[wv] = s; rgx[wv] = gx; rgy[wv] = gy;
  }
  __syncthreads();
  float S = rs[0] + rs[1] + rs[2] + rs[3];
  if (act) corrws[pix * 169 + tid] = e / S;
  if (tid == 0) {
    grid[pix * 2 + 0] = (rgx[0] + rgx[1] + rgx[2] + rgx[3]) / S;
    grid[pix * 2 + 1] = (rgy[0] + rgy[1] + rgy[2] + rgy[3]) / S;
  }
}

// ---------------------------------------------------------------------------
// K2b: refs 1,2. Block = 4 consecutive pixels of row y; union tap grid
// 13 rows x 16 cols = 208 r-positions (vs 4x169). Then wave-per-pixel
// gaussian softmax + grid.
__global__ __launch_bounds__(256) void k_corrk4(
    const float* __restrict__ tT, const float* __restrict__ rT,
    float* __restrict__ corrws, float* __restrict__ grid) {
  int xg = blockIdx.x, y = blockIdx.y;
  int k = blockIdx.z + 1;
  int x0 = xg * 4;
  int tid = threadIdx.x;
  int g = tid >> 2, tx = tid & 3;
  __shared__ float cc[4][169];
  for (int i = tid; i < 676; i += 256) ((float*)&cc[0][0])[i] = 0.f;

  const float4* tp0 = (const float4*)&tT[(y * 64 + x0 + 0) * 64];
  const float4* tp1 = (const float4*)&tT[(y * 64 + x0 + 1) * 64];
  const float4* tp2 = (const float4*)&tT[(y * 64 + x0 + 2) * 64];
  const float4* tp3 = (const float4*)&tT[(y * 64 + x0 + 3) * 64];
  float4 t00 = tp0[tx], t01 = tp0[tx + 4], t02 = tp0[tx + 8], t03 = tp0[tx + 12];
  float4 t10 = tp1[tx], t11 = tp1[tx + 4], t12 = tp1[tx + 8], t13 = tp1[tx + 12];
  float4 t20 = tp2[tx], t21 = tp2[tx + 4], t22 = tp2[tx + 8], t23 = tp2[tx + 12];
  float4 t30 = tp3[tx], t31 = tp3[tx + 4], t32 = tp3[tx + 8], t33 = tp3[tx + 12];
  const float* rbase = rT + k * (64 * NPIX);
  __syncthreads();

#pragma unroll 1
  for (int r = 0; r < 4; ++r) {
    int tu = g + r * 64;
    if (tu < 208) {
      int i = tu >> 4, u = tu & 15;
      int ry = y + i - 6;
      int rx = x0 - 6 + u;
      if ((unsigned)ry < 64u && (unsigned)rx < 64u) {
        const float4* rp = (const float4*)&rbase[(ry * 64 + rx) * 64];
        float4 ra = rp[tx], rb = rp[tx + 4], rc = rp[tx + 8], rd = rp[tx + 12];
        float p0 = pdot(t00, t01, t02, t03, ra, rb, rc, rd);
        float p1 = pdot(t10, t11, t12, t13, ra, rb, rc, rd);
        float p2 = pdot(t20, t21, t22, t23, ra, rb, rc, rd);
        float p3 = pdot(t30, t31, t32, t33, ra, rb, rc, rd);
        float v = xpose_reduce4(p0, p1, p2, p3, tx);
        int j = u - tx;  // lane tx owns pixel tx
        if ((unsigned)j < 13u) cc[tx][i * 13 + j] = v;
      }
    }
  }
  __syncthreads();

  // one wave per pixel: gaussian-weighted softmax + grid
  int w = tid >> 6, lane = tid & 63;
  int pix = y * 64 + x0 + w;
  int y0 = y, x = x0 + w;
  float sc[3];
  float lmax = -3e38f;
#pragma unroll
  for (int it = 0; it < 3; ++it) {
    int o = lane + it * 64;
    float scv = -3e38f;
    if (o < 169) {
      int i = o / 13, j = o - i * 13;
      float di = (float)((i - 6) * (i - 6) + (j - 6) * (j - 6));
      scv = 50.f * __expf(-0.5f * di) * cc[w][o];
    }
    sc[it] = scv;
    lmax = fmaxf(lmax, scv);
  }
#pragma unroll
  for (int o = 32; o; o >>= 1) lmax = fmaxf(lmax, __shfl_down(lmax, o));
  float m = __shfl(lmax, 0);
  float ee[3];
  float s = 0.f, gx = 0.f, gy = 0.f;
#pragma unroll
  for (int it = 0; it < 3; ++it) {
    int o = lane + it * 64;
    int i = o / 13, j = o - i * 13;
    float e = __expf(sc[it] - m);
    ee[it] = e;
    int yy = y0 + i - 6, xx = x + j - 6;
    bool inb = (o < 169) && (unsigned)yy < 64u && (unsigned)xx < 64u;
    float xgv = inb ? (-1.f + (2.f / 63.f) * (float)xx) : 0.f;
    float ygv = inb ? (-1.f + (2.f / 63.f) * (float)yy) : 0.f;
    s += e;
    gx += e * xgv;
    gy += e * ygv;
  }
#pragma unroll
  for (int o = 32; o; o >>= 1) {
    s += __shfl_down(s, o);
    gx += __shfl_down(gx, o);
    gy += __shfl_down(gy, o);
  }
  float S = __shfl(s, 0);
#pragma unroll
  for (int it = 0; it < 3; ++it) {
    int o = lane + it * 64;
    if (o < 169) corrws[(k * NPIX + pix) * 169 + o] = ee[it] / S;
  }
  if (lane == 0) {
    grid[(k * NPIX + pix) * 2 + 0] = gx / S;
    grid[(k * NPIX + pix) * 2 + 1] = gy / S;
  }
}

// ---------------------------------------------------------------------------
// K3: out[c,pix] via per-pixel 32-bin LDS histogram. Ref0 uses the inverse
// bilinear factorization: each of the 196 grid positions gets one label load
// and one atomicAdd with the 4-tap-combined weight.
__global__ __launch_bounds__(256) void k_out(const float* __restrict__ corrws,
                                             const float* __restrict__ off,
                                             const int* __restrict__ q,
                                             float* __restrict__ out) {
  int tid = threadIdx.x;
  int pix0 = blockIdx.x * 8;
  __shared__ float bins[8][32];
  __shared__ float cr[8][169];
  __shared__ float offs[8][2];
  bins[tid >> 5][tid & 31] = 0.f;
  if (tid < 16) offs[tid >> 1][tid & 1] = off[(pix0 + (tid >> 1)) * 2 + (tid & 1)];
  for (int i = tid; i < 8 * 169; i += 256) {
    int g = i / 169, n = i - g * 169;
    cr[g][n] = corrws[(pix0 + g) * 169 + n];
  }
  __syncthreads();

  // ref0: 8 pixels x 196 grid positions
  for (int s = tid; s < 8 * 196; s += 256) {
    int g = s / 196, m = s - g * 196;
    int a = m / 14, b = m - a * 14;
    int pix = pix0 + g, y = pix >> 6, x = pix & 63;
    float offx = offs[g][0], offy = offs[g][1];
    float fy = floorf(offy), fx = floorf(offx);
    float wy = offy - fy, wx = offx - fx;
    int ry = y + (int)fy - 6 + a, rx = x + (int)fx - 6 + b;
    if ((unsigned)ry < 64u && (unsigned)rx < 64u) {
      float w00 = (1.f - wy) * (1.f - wx), w01 = (1.f - wy) * wx;
      float w10 = wy * (1.f - wx), w11 = wy * wx;
      float wgt = 0.f;
      if (a < 13) {
        if (b < 13) wgt = fmaf(w00, cr[g][a * 13 + b], wgt);
        if (b > 0) wgt = fmaf(w01, cr[g][a * 13 + b - 1], wgt);
      }
      if (a > 0) {
        if (b < 13) wgt = fmaf(w10, cr[g][(a - 1) * 13 + b], wgt);
        if (b > 0) wgt = fmaf(w11, cr[g][(a - 1) * 13 + b - 1], wgt);
      }
      if (wgt != 0.f) {
        int lbl = q[ry * 1024 + rx * 4];
        atomicAdd(&bins[g][lbl], wgt);
      }
    }
  }

  // refs 1,2: integer taps
  for (int k = 1; k < 3; ++k) {
    __syncthreads();
    for (int i = tid; i < 8 * 169; i += 256) {
      int g = i / 169, n = i - g * 169;
      cr[g][n] = corrws[((k << 12) + pix0 + g) * 169 + n];
    }
    __syncthreads();
    for (int s = tid; s < 8 * 169; s += 256) {
      int g = s / 169, n = s - g * 169;
      int i2 = n / 13, j2 = n - i2 * 13;
      int pix = pix0 + g, y = pix >> 6, x = pix & 63;
      int yy = y + i2 - 6, xx = x + j2 - 6;
      if ((unsigned)yy < 64u && (unsigned)xx < 64u) {
        int lbl = q[k * 65536 + yy * 1024 + xx * 4];
        atomicAdd(&bins[g][lbl], cr[g][n]);
      }
    }
  }
  __syncthreads();
  out[(tid >> 3) * NPIX + pix0 + (tid & 7)] = bins[tid & 7][tid >> 3];
}

// ---------------------------------------------------------------------------
extern "C" void kernel_launch(void* const* d_in, const int* in_sizes, int n_in,
                              void* d_out, int out_size, void* d_ws,
                              size_t ws_size, hipStream_t stream) {
  const float* fr = (const float*)d_in[0];  // feats_r (3,1,64,64,64)
  const float* ft = (const float*)d_in[1];  // feats_t (1,64,64,64)
  const int* q = (const int*)d_in[2];       // quantized_r (3,1,1,256,256)
  float* out = (float*)d_out;               // 131072 + 24576 floats
  float* grid = out + 32 * NPIX;

  float* ws = (float*)d_ws;
  float* tT = ws;                  // 4096*64
  float* rT = ws + 262144;         // 3*4096*64
  float* off = ws + 1048576;       // 4096*2
  float* corrws = ws + 1056768;    // 3*4096*169

  k_transpose<<<dim3(64, 4), 256, 0, stream>>>(ft, fr, tT, rT);
  k_off4<<<dim3(16, 64), 256, 0, stream>>>(tT, rT, off);
  k_corr0<<<NPIX, 256, 0, stream>>>(tT, rT, off, corrws, grid);
  k_corrk4<<<dim3(16, 64, 2), 256, 0, stream>>>(tT, rT, corrws, grid);
  k_out<<<512, 256, 0, stream>>>(corrws, off, q, out);
}

// Round 4
// 62.540 us; speedup vs baseline: 6.0581x; 1.0883x over previous
//
#include <hip/hip_runtime.h>

// Problem constants (fixed inputs: ref_index=[0,1,2], current_ind=16)
// -> nsearch=1, dirates=[2], nref=3
// feats_r: (3,1,64,64,64) f32, feats_t: (1,64,64,64) f32,
// quantized_r: (3,1,1,256,256) i32
// out: (1,32,64,64) f32 then grid: (3,64,64,2) f32

#define NPIX 4096   // 64*64

// 16-channel partial dot (this lane's quarter of the 64-ch dot).
__device__ __forceinline__ float pdot(float4 t0, float4 t1, float4 t2,
                                      float4 t3, float4 a, float4 b, float4 c,
                                      float4 d) {
  float s0 = 0.f, s1 = 0.f, s2 = 0.f, s3 = 0.f;
  s0 = fmaf(t0.x, a.x, s0); s1 = fmaf(t0.y, a.y, s1);
  s2 = fmaf(t0.z, a.z, s2); s3 = fmaf(t0.w, a.w, s3);
  s0 = fmaf(t1.x, b.x, s0); s1 = fmaf(t1.y, b.y, s1);
  s2 = fmaf(t1.z, b.z, s2); s3 = fmaf(t1.w, b.w, s3);
  s0 = fmaf(t2.x, c.x, s0); s1 = fmaf(t2.y, c.y, s1);
  s2 = fmaf(t2.z, c.z, s2); s3 = fmaf(t2.w, c.w, s3);
  s0 = fmaf(t3.x, d.x, s0); s1 = fmaf(t3.y, d.y, s1);
  s2 = fmaf(t3.z, d.z, s2); s3 = fmaf(t3.w, d.w, s3);
  return (s0 + s1) + (s2 + s3);
}

// 4-lane cooperative dot (all lanes get result).
__device__ __forceinline__ float qdot(float4 ta, float4 tb, float4 tc,
                                      float4 td,
                                      const float* __restrict__ rbase,
                                      int tx) {
  const float4* r = (const float4*)rbase;
  float v = pdot(ta, tb, tc, td, r[tx], r[tx + 4], r[tx + 8], r[tx + 12]);
  v += __shfl_xor(v, 1);
  v += __shfl_xor(v, 2);
  return v;
}

// 4-lane transpose-reduce: input p0..p3 = this lane's 16-ch partials for
// pixels 0..3; output: lane tx holds the full 64-ch dot of pixel tx.
__device__ __forceinline__ float xpose_reduce4(float p0, float p1, float p2,
                                               float p3, int tx) {
  bool o1 = tx & 1, o2 = tx & 2;
  float x01 = __shfl_xor(o1 ? p0 : p1, 1);
  float x23 = __shfl_xor(o1 ? p2 : p3, 1);
  float sA = (o1 ? p1 : p0) + x01;
  float sB = (o1 ? p3 : p2) + x23;
  float z = __shfl_xor(o2 ? sA : sB, 2);
  return o2 ? (sB + z) : (sA + z);
}

// ---------------------------------------------------------------------------
// K0: transpose [c][pix] -> [pix][c] for feats_t and the 3 feats_r refs.
__global__ __launch_bounds__(256) void k_transpose(
    const float* __restrict__ ft, const float* __restrict__ fr,
    float* __restrict__ tT, float* __restrict__ rT) {
  __shared__ float tile[64][65];
  int img = blockIdx.y;
  int pixBase = blockIdx.x * 64;
  const float* src = (img == 0) ? ft : fr + (img - 1) * (64 * NPIX);
  float* dst = (img == 0) ? tT : rT + (img - 1) * (64 * NPIX);
  int tid = threadIdx.x;
#pragma unroll
  for (int it = 0; it < 16; ++it) {
    int li = it * 256 + tid;
    int c = li >> 6, p = li & 63;
    tile[p][c] = src[c * NPIX + pixBase + p];
  }
  __syncthreads();
#pragma unroll
  for (int it = 0; it < 16; ++it) {
    int li = it * 256 + tid;
    int p = li >> 6, c = li & 63;
    dst[(pixBase + p) * 64 + c] = tile[p][c];
  }
}

// t-fragment loader: 16 ch (4 float4) of pixel (row y, col xc) into 4 regs.
#define LOADT(N, XC)                                                       \
  const float4* tp##N = (const float4*)&tT[((y << 6) + (XC)) << 6];        \
  float4 t##N##0 = tp##N[tx], t##N##1 = tp##N[tx + 4],                     \
         t##N##2 = tp##N[tx + 8], t##N##3 = tp##N[tx + 12];

// ---------------------------------------------------------------------------
// K1: fused correlation kernel. grid (8, 64, 3).
//  z=0: 8 same-parity pixels {x0+0,2,..,14}: 25x32-union offset dots ->
//       softmax-expectation -> offsets -> 196-grid deformed dots ->
//       gaussian softmax -> corrws[0], grid[0], off[].
//  z=1,2: 8 consecutive pixels: 13x20-union dots -> gaussian softmax ->
//       corrws[z], grid[z].
__global__ __launch_bounds__(256) void k_corr_all(
    const float* __restrict__ tT, const float* __restrict__ rT,
    float* __restrict__ off, float* __restrict__ corrws,
    float* __restrict__ grid) {
  int z = blockIdx.z;
  int xg = blockIdx.x, y = blockIdx.y;
  int tid = threadIdx.x;
  int g = tid >> 2, tx = tid & 3;
  int w = tid >> 6, lane = tid & 63;
  __shared__ float cc[8][625];   // 20 KB; z>=1 aliases as [8][169]
  __shared__ float offs[8][2];

  if (z == 0) {
    int x0 = (xg >> 1) * 16 + (xg & 1);  // pixels x0 + {0,2,...,14}
    LOADT(0, x0 + 0)  LOADT(1, x0 + 2)  LOADT(2, x0 + 4)  LOADT(3, x0 + 6)
    LOADT(4, x0 + 8)  LOADT(5, x0 + 10) LOADT(6, x0 + 12) LOADT(7, x0 + 14)

    // --- phase 1: 25x32 union dilated dots -> cc[8][625] (no init needed:
    // every (pixel,tap) is written exactly once; OOB-r taps written as 0).
#pragma unroll 2
    for (int r = 0; r < 13; ++r) {
      int tu = g + r * 64;
      if (tu < 800) {
        int oy = tu >> 5, u = tu & 31;
        int ry = y + 2 * (oy - 12), rx = x0 - 24 + 2 * u;
        float4 ra, rb, rc, rd;
        if ((unsigned)ry < 64u && (unsigned)rx < 64u) {
          const float4* rp = (const float4*)&rT[(ry * 64 + rx) * 64];
          ra = rp[tx]; rb = rp[tx + 4]; rc = rp[tx + 8]; rd = rp[tx + 12];
        } else {
          ra = rb = rc = rd = make_float4(0.f, 0.f, 0.f, 0.f);
        }
        float p0 = pdot(t00, t01, t02, t03, ra, rb, rc, rd);
        float p1 = pdot(t10, t11, t12, t13, ra, rb, rc, rd);
        float p2 = pdot(t20, t21, t22, t23, ra, rb, rc, rd);
        float p3 = pdot(t30, t31, t32, t33, ra, rb, rc, rd);
        float p4 = pdot(t40, t41, t42, t43, ra, rb, rc, rd);
        float p5 = pdot(t50, t51, t52, t53, ra, rb, rc, rd);
        float p6 = pdot(t60, t61, t62, t63, ra, rb, rc, rd);
        float p7 = pdot(t70, t71, t72, t73, ra, rb, rc, rd);
        float dlo = xpose_reduce4(p0, p1, p2, p3, tx);
        float dhi = xpose_reduce4(p4, p5, p6, p7, tx);
        int ox = u - tx;
        if ((unsigned)ox < 25u) cc[tx][oy * 25 + ox] = dlo;
        int ox2 = u - tx - 4;
        if ((unsigned)ox2 < 25u) cc[tx + 4][oy * 25 + ox2] = dhi;
      }
    }
    __syncthreads();

    // --- phase 2: per-pixel softmax expectation (wave w -> pixels w, w+4)
#pragma unroll 1
    for (int pass = 0; pass < 2; ++pass) {
      int pw = w + 4 * pass;
      float vv[10];
      float lmax = -3e38f;
#pragma unroll
      for (int it = 0; it < 10; ++it) {
        int o = lane + it * 64;
        float v = (o < 625) ? cc[pw][o] : -3e38f;
        vv[it] = v;
        lmax = fmaxf(lmax, v);
      }
#pragma unroll
      for (int o = 32; o; o >>= 1) lmax = fmaxf(lmax, __shfl_down(lmax, o));
      float m = __shfl(lmax, 0);
      float s = 0.f, sx = 0.f, sy = 0.f;
#pragma unroll
      for (int it = 0; it < 10; ++it) {
        int o = lane + it * 64;
        int oy = o / 25, ox = o - oy * 25;
        float e = __expf(vv[it] - m);
        s += e;
        sx += e * (float)(ox - 12);
        sy += e * (float)(oy - 12);
      }
#pragma unroll
      for (int o = 32; o; o >>= 1) {
        s += __shfl_down(s, o);
        sx += __shfl_down(sx, o);
        sy += __shfl_down(sy, o);
      }
      if (lane == 0) {
        float ox_ = 2.f * sx / s, oy_ = 2.f * sy / s;
        offs[pw][0] = ox_;
        offs[pw][1] = oy_;
        int pix = y * 64 + x0 + 2 * pw;
        off[pix * 2 + 0] = ox_;
        off[pix * 2 + 1] = oy_;
      }
    }
    __syncthreads();

    // --- phase 3: deformed 14x14 dot grids (8 px x 196), reuse cc as D
    float(*D)[196] = (float(*)[196]) & cc[0][0];
#pragma unroll 1
    for (int r = 0; r < 25; ++r) {
      int s = g + r * 64;
      if (s < 1568) {
        int p = s / 196;
        int idx = s - p * 196;
        int a = idx / 14, b2 = idx - a * 14;
        float offx = offs[p][0], offy = offs[p][1];
        int px = x0 + 2 * p;
        int iy0 = y + (int)floorf(offy), ix0 = px + (int)floorf(offx);
        int ry = iy0 - 6 + a, rx = ix0 - 6 + b2;
        float v = 0.f;
        if ((unsigned)ry < 64u && (unsigned)rx < 64u) {
          const float4* tq = (const float4*)&tT[(y * 64 + px) * 64];
          v = qdot(tq[tx], tq[tx + 4], tq[tx + 8], tq[tx + 12],
                   &rT[(ry * 64 + rx) * 64], tx);
        }
        if (tx == 0) D[p][idx] = v;
      }
    }
    __syncthreads();

    // --- phase 4: gaussian softmax + grid for ref0 (wave w -> px w, w+4)
#pragma unroll 1
    for (int pass = 0; pass < 2; ++pass) {
      int pw = w + 4 * pass;
      int px = x0 + 2 * pw;
      int pix = y * 64 + px;
      float offx = offs[pw][0], offy = offs[pw][1];
      float fy = floorf(offy), fx = floorf(offx);
      float wy = offy - fy, wx = offx - fx;
      float w00 = (1.f - wy) * (1.f - wx), w01 = (1.f - wy) * wx;
      float w10 = wy * (1.f - wx), w11 = wy * wx;
      float sc[3];
      float lmax = -3e38f;
#pragma unroll
      for (int it = 0; it < 3; ++it) {
        int o = lane + it * 64;
        float scv = -3e38f;
        if (o < 169) {
          int i = o / 13, j = o - i * 13;
          float v = w00 * D[pw][i * 14 + j] + w01 * D[pw][i * 14 + j + 1] +
                    w10 * D[pw][(i + 1) * 14 + j] +
                    w11 * D[pw][(i + 1) * 14 + j + 1];
          float di = (float)((i - 6) * (i - 6) + (j - 6) * (j - 6));
          scv = 50.f * __expf(-0.5f * di) * v;
        }
        sc[it] = scv;
        lmax = fmaxf(lmax, scv);
      }
#pragma unroll
      for (int o = 32; o; o >>= 1) lmax = fmaxf(lmax, __shfl_down(lmax, o));
      float m = __shfl(lmax, 0);
      float ee[3];
      float s = 0.f, gx = 0.f, gy = 0.f;
#pragma unroll
      for (int it = 0; it < 3; ++it) {
        int o = lane + it * 64;
        int i = o / 13, j = o - i * 13;
        float e = __expf(sc[it] - m);
        ee[it] = e;
        int yy = y + i - 6, xx = px + j - 6;
        bool inb = (o < 169) && (unsigned)yy < 64u && (unsigned)xx < 64u;
        float xgv = inb ? (-1.f + (2.f / 63.f) * (float)xx) : 0.f;
        float ygv = inb ? (-1.f + (2.f / 63.f) * (float)yy) : 0.f;
        s += e;
        gx += e * xgv;
        gy += e * ygv;
      }
#pragma unroll
      for (int o = 32; o; o >>= 1) {
        s += __shfl_down(s, o);
        gx += __shfl_down(gx, o);
        gy += __shfl_down(gy, o);
      }
      float S = __shfl(s, 0);
#pragma unroll
      for (int it = 0; it < 3; ++it) {
        int o = lane + it * 64;
        if (o < 169) corrws[pix * 169 + o] = ee[it] / S;
      }
      if (lane == 0) {
        grid[pix * 2 + 0] = __shfl(gx, 0) / S;
        grid[pix * 2 + 1] = __shfl(gy, 0) / S;
      }
    }
  } else {
    // ---- refs 1,2: 8 consecutive pixels, 13x20 union ----
    int k = z;
    int x0 = xg * 8;
    const float* rb0 = rT + k * (64 * NPIX);
    LOADT(0, x0 + 0)  LOADT(1, x0 + 1)  LOADT(2, x0 + 2)  LOADT(3, x0 + 3)
    LOADT(4, x0 + 4)  LOADT(5, x0 + 5)  LOADT(6, x0 + 6)  LOADT(7, x0 + 7)
    float(*cc2)[169] = (float(*)[169]) & cc[0][0];

#pragma unroll 2
    for (int r = 0; r < 5; ++r) {
      int tu = g + r * 64;
      if (tu < 260) {
        int i = tu / 20, u = tu - i * 20;
        int ry = y + i - 6, rx = x0 - 6 + u;
        float4 ra, rbv, rc, rd;
        if ((unsigned)ry < 64u && (unsigned)rx < 64u) {
          const float4* rp = (const float4*)&rb0[(ry * 64 + rx) * 64];
          ra = rp[tx]; rbv = rp[tx + 4]; rc = rp[tx + 8]; rd = rp[tx + 12];
        } else {
          ra = rbv = rc = rd = make_float4(0.f, 0.f, 0.f, 0.f);
        }
        float p0 = pdot(t00, t01, t02, t03, ra, rbv, rc, rd);
        float p1 = pdot(t10, t11, t12, t13, ra, rbv, rc, rd);
        float p2 = pdot(t20, t21, t22, t23, ra, rbv, rc, rd);
        float p3 = pdot(t30, t31, t32, t33, ra, rbv, rc, rd);
        float p4 = pdot(t40, t41, t42, t43, ra, rbv, rc, rd);
        float p5 = pdot(t50, t51, t52, t53, ra, rbv, rc, rd);
        float p6 = pdot(t60, t61, t62, t63, ra, rbv, rc, rd);
        float p7 = pdot(t70, t71, t72, t73, ra, rbv, rc, rd);
        float dlo = xpose_reduce4(p0, p1, p2, p3, tx);
        float dhi = xpose_reduce4(p4, p5, p6, p7, tx);
        int j = u - tx;
        if ((unsigned)j < 13u) cc2[tx][i * 13 + j] = dlo;
        int j2 = u - tx - 4;
        if ((unsigned)j2 < 13u) cc2[tx + 4][i * 13 + j2] = dhi;
      }
    }
    __syncthreads();

#pragma unroll 1
    for (int pass = 0; pass < 2; ++pass) {
      int pw = w + 4 * pass;
      int px = x0 + pw;
      int pix = y * 64 + px;
      float sc[3];
      float lmax = -3e38f;
#pragma unroll
      for (int it = 0; it < 3; ++it) {
        int o = lane + it * 64;
        float scv = -3e38f;
        if (o < 169) {
          int i = o / 13, j = o - i * 13;
          float di = (float)((i - 6) * (i - 6) + (j - 6) * (j - 6));
          scv = 50.f * __expf(-0.5f * di) * cc2[pw][o];
        }
        sc[it] = scv;
        lmax = fmaxf(lmax, scv);
      }
#pragma unroll
      for (int o = 32; o; o >>= 1) lmax = fmaxf(lmax, __shfl_down(lmax, o));
      float m = __shfl(lmax, 0);
      float ee[3];
      float s = 0.f, gx = 0.f, gy = 0.f;
#pragma unroll
      for (int it = 0; it < 3; ++it) {
        int o = lane + it * 64;
        int i = o / 13, j = o - i * 13;
        float e = __expf(sc[it] - m);
        ee[it] = e;
        int yy = y + i - 6, xx = px + j - 6;
        bool inb = (o < 169) && (unsigned)yy < 64u && (unsigned)xx < 64u;
        float xgv = inb ? (-1.f + (2.f / 63.f) * (float)xx) : 0.f;
        float ygv = inb ? (-1.f + (2.f / 63.f) * (float)yy) : 0.f;
        s += e;
        gx += e * xgv;
        gy += e * ygv;
      }
#pragma unroll
      for (int o = 32; o; o >>= 1) {
        s += __shfl_down(s, o);
        gx += __shfl_down(gx, o);
        gy += __shfl_down(gy, o);
      }
      float S = __shfl(s, 0);
#pragma unroll
      for (int it = 0; it < 3; ++it) {
        int o = lane + it * 64;
        if (o < 169) corrws[(k * NPIX + pix) * 169 + o] = ee[it] / S;
      }
      if (lane == 0) {
        grid[(k * NPIX + pix) * 2 + 0] = __shfl(gx, 0) / S;
        grid[(k * NPIX + pix) * 2 + 1] = __shfl(gy, 0) / S;
      }
    }
  }
}

// ---------------------------------------------------------------------------
// K3: out[c,pix] via per-pixel 32-bin LDS histogram. Ref0 uses the inverse
// bilinear factorization: each of the 196 grid positions gets one label load
// and one atomicAdd with the 4-tap-combined weight.
__global__ __launch_bounds__(256) void k_out(const float* __restrict__ corrws,
                                             const float* __restrict__ off,
                                             const int* __restrict__ q,
                                             float* __restrict__ out) {
  int tid = threadIdx.x;
  int pix0 = blockIdx.x * 8;
  __shared__ float bins[8][32];
  __shared__ float cr[8][169];
  __shared__ float offs[8][2];
  bins[tid >> 5][tid & 31] = 0.f;
  if (tid < 16) offs[tid >> 1][tid & 1] = off[(pix0 + (tid >> 1)) * 2 + (tid & 1)];
  for (int i = tid; i < 8 * 169; i += 256) {
    int g = i / 169, n = i - g * 169;
    cr[g][n] = corrws[(pix0 + g) * 169 + n];
  }
  __syncthreads();

  // ref0: 8 pixels x 196 grid positions
  for (int s = tid; s < 8 * 196; s += 256) {
    int g = s / 196, m = s - g * 196;
    int a = m / 14, b = m - a * 14;
    int pix = pix0 + g, y = pix >> 6, x = pix & 63;
    float offx = offs[g][0], offy = offs[g][1];
    float fy = floorf(offy), fx = floorf(offx);
    float wy = offy - fy, wx = offx - fx;
    int ry = y + (int)fy - 6 + a, rx = x + (int)fx - 6 + b;
    if ((unsigned)ry < 64u && (unsigned)rx < 64u) {
      float w00 = (1.f - wy) * (1.f - wx), w01 = (1.f - wy) * wx;
      float w10 = wy * (1.f - wx), w11 = wy * wx;
      float wgt = 0.f;
      if (a < 13) {
        if (b < 13) wgt = fmaf(w00, cr[g][a * 13 + b], wgt);
        if (b > 0) wgt = fmaf(w01, cr[g][a * 13 + b - 1], wgt);
      }
      if (a > 0) {
        if (b < 13) wgt = fmaf(w10, cr[g][(a - 1) * 13 + b], wgt);
        if (b > 0) wgt = fmaf(w11, cr[g][(a - 1) * 13 + b - 1], wgt);
      }
      if (wgt != 0.f) {
        int lbl = q[ry * 1024 + rx * 4];
        atomicAdd(&bins[g][lbl], wgt);
      }
    }
  }

  // refs 1,2: integer taps
  for (int k = 1; k < 3; ++k) {
    __syncthreads();
    for (int i = tid; i < 8 * 169; i += 256) {
      int g = i / 169, n = i - g * 169;
      cr[g][n] = corrws[((k << 12) + pix0 + g) * 169 + n];
    }
    __syncthreads();
    for (int s = tid; s < 8 * 169; s += 256) {
      int g = s / 169, n = s - g * 169;
      int i2 = n / 13, j2 = n - i2 * 13;
      int pix = pix0 + g, y = pix >> 6, x = pix & 63;
      int yy = y + i2 - 6, xx = x + j2 - 6;
      if ((unsigned)yy < 64u && (unsigned)xx < 64u) {
        int lbl = q[k * 65536 + yy * 1024 + xx * 4];
        atomicAdd(&bins[g][lbl], cr[g][n]);
      }
    }
  }
  __syncthreads();
  out[(tid >> 3) * NPIX + pix0 + (tid & 7)] = bins[tid & 7][tid >> 3];
}

// ---------------------------------------------------------------------------
extern "C" void kernel_launch(void* const* d_in, const int* in_sizes, int n_in,
                              void* d_out, int out_size, void* d_ws,
                              size_t ws_size, hipStream_t stream) {
  const float* fr = (const float*)d_in[0];  // feats_r (3,1,64,64,64)
  const float* ft = (const float*)d_in[1];  // feats_t (1,64,64,64)
  const int* q = (const int*)d_in[2];       // quantized_r (3,1,1,256,256)
  float* out = (float*)d_out;               // 131072 + 24576 floats
  float* grid = out + 32 * NPIX;

  float* ws = (float*)d_ws;
  float* tT = ws;                  // 4096*64
  float* rT = ws + 262144;         // 3*4096*64
  float* off = ws + 1048576;       // 4096*2
  float* corrws = ws + 1056768;    // 3*4096*169

  k_transpose<<<dim3(64, 4), 256, 0, stream>>>(ft, fr, tT, rT);
  k_corr_all<<<dim3(8, 64, 3), 256, 0, stream>>>(tT, rT, off, corrws, grid);
  k_out<<<512, 256, 0, stream>>>(corrws, off, q, out);
}

// Round 5
// 61.444 us; speedup vs baseline: 6.1661x; 1.0178x over previous
//
#include <hip/hip_runtime.h>

// Problem constants (fixed inputs: ref_index=[0,1,2], current_ind=16)
// -> nsearch=1, dirates=[2], nref=3
// feats_r: (3,1,64,64,64) f32, feats_t: (1,64,64,64) f32,
// quantized_r: (3,1,1,256,256) i32
// out: (1,32,64,64) f32 then grid: (3,64,64,2) f32

#define NPIX 4096   // 64*64

// 16-channel partial dot (this lane's quarter of the 64-ch dot).
__device__ __forceinline__ float pdot(float4 t0, float4 t1, float4 t2,
                                      float4 t3, float4 a, float4 b, float4 c,
                                      float4 d) {
  float s0 = 0.f, s1 = 0.f, s2 = 0.f, s3 = 0.f;
  s0 = fmaf(t0.x, a.x, s0); s1 = fmaf(t0.y, a.y, s1);
  s2 = fmaf(t0.z, a.z, s2); s3 = fmaf(t0.w, a.w, s3);
  s0 = fmaf(t1.x, b.x, s0); s1 = fmaf(t1.y, b.y, s1);
  s2 = fmaf(t1.z, b.z, s2); s3 = fmaf(t1.w, b.w, s3);
  s0 = fmaf(t2.x, c.x, s0); s1 = fmaf(t2.y, c.y, s1);
  s2 = fmaf(t2.z, c.z, s2); s3 = fmaf(t2.w, c.w, s3);
  s0 = fmaf(t3.x, d.x, s0); s1 = fmaf(t3.y, d.y, s1);
  s2 = fmaf(t3.z, d.z, s2); s3 = fmaf(t3.w, d.w, s3);
  return (s0 + s1) + (s2 + s3);
}

// 4-lane cooperative dot (all lanes get result).
__device__ __forceinline__ float qdot(float4 ta, float4 tb, float4 tc,
                                      float4 td,
                                      const float* __restrict__ rbase,
                                      int tx) {
  const float4* r = (const float4*)rbase;
  float v = pdot(ta, tb, tc, td, r[tx], r[tx + 4], r[tx + 8], r[tx + 12]);
  v += __shfl_xor(v, 1);
  v += __shfl_xor(v, 2);
  return v;
}

// 4-lane transpose-reduce: input p0..p3 = this lane's 16-ch partials for
// pixels 0..3; output: lane tx holds the full 64-ch dot of pixel tx.
__device__ __forceinline__ float xpose_reduce4(float p0, float p1, float p2,
                                               float p3, int tx) {
  bool o1 = tx & 1, o2 = tx & 2;
  float x01 = __shfl_xor(o1 ? p0 : p1, 1);
  float x23 = __shfl_xor(o1 ? p2 : p3, 1);
  float sA = (o1 ? p1 : p0) + x01;
  float sB = (o1 ? p3 : p2) + x23;
  float z = __shfl_xor(o2 ? sA : sB, 2);
  return o2 ? (sB + z) : (sA + z);
}

// ---------------------------------------------------------------------------
// K0: transpose [c][pix] -> [pix][c] for feats_t and the 3 feats_r refs.
__global__ __launch_bounds__(256) void k_transpose(
    const float* __restrict__ ft, const float* __restrict__ fr,
    float* __restrict__ tT, float* __restrict__ rT) {
  __shared__ float tile[64][65];
  int img = blockIdx.y;
  int pixBase = blockIdx.x * 64;
  const float* src = (img == 0) ? ft : fr + (img - 1) * (64 * NPIX);
  float* dst = (img == 0) ? tT : rT + (img - 1) * (64 * NPIX);
  int tid = threadIdx.x;
#pragma unroll
  for (int it = 0; it < 16; ++it) {
    int li = it * 256 + tid;
    int c = li >> 6, p = li & 63;
    tile[p][c] = src[c * NPIX + pixBase + p];
  }
  __syncthreads();
#pragma unroll
  for (int it = 0; it < 16; ++it) {
    int li = it * 256 + tid;
    int p = li >> 6, c = li & 63;
    dst[(pixBase + p) * 64 + c] = tile[p][c];
  }
}

// t-fragment loader: 16 ch (4 float4) of pixel (row y, col xc) into 4 regs.
#define LOADT(N, XC)                                                       \
  const float4* tp##N = (const float4*)&tT[((y << 6) + (XC)) << 6];        \
  float4 t##N##0 = tp##N[tx], t##N##1 = tp##N[tx + 4],                     \
         t##N##2 = tp##N[tx + 8], t##N##3 = tp##N[tx + 12];

// ---------------------------------------------------------------------------
// K1: fused correlation kernel. grid (16, 64, 3), 4 pixels per block.
//  z=0: 4 same-parity pixels {x0,x0+2,x0+4,x0+6}: 25x28-union offset dots ->
//       softmax-expectation -> offsets -> 4x196 deformed dots ->
//       gaussian softmax -> corrws[0], grid[0], off[].
//  z=1,2: 4 consecutive pixels: 13x16-union dots -> gaussian softmax.
__global__ __launch_bounds__(256) void k_corr_all(
    const float* __restrict__ tT, const float* __restrict__ rT,
    float* __restrict__ off, float* __restrict__ corrws,
    float* __restrict__ grid) {
  int z = blockIdx.z;
  int xg = blockIdx.x, y = blockIdx.y;
  int tid = threadIdx.x;
  int g = tid >> 2, tx = tid & 3;
  int w = tid >> 6, lane = tid & 63;
  __shared__ float cc[4][625];   // 10 KB; z>=1 aliases as [4][169]
  __shared__ float offs[4][2];

  if (z == 0) {
    int x0 = (xg >> 1) * 8 + (xg & 1);  // pixels x0 + {0,2,4,6}
    LOADT(0, x0 + 0) LOADT(1, x0 + 2) LOADT(2, x0 + 4) LOADT(3, x0 + 6)

    // --- phase 1: 25x28 union dilated dots -> cc[4][625] (every (px,tap)
    // written exactly once; OOB-r taps get v=0 via zero r-vectors).
#pragma unroll 2
    for (int r = 0; r < 11; ++r) {
      int tu = g + (r << 6);
      if (tu < 700) {
        int oy = tu / 28, u = tu - oy * 28;
        int ry = y + 2 * (oy - 12), rx = x0 - 24 + 2 * u;
        float4 ra, rb, rc, rd;
        if ((unsigned)ry < 64u && (unsigned)rx < 64u) {
          const float4* rp = (const float4*)&rT[(ry * 64 + rx) * 64];
          ra = rp[tx]; rb = rp[tx + 4]; rc = rp[tx + 8]; rd = rp[tx + 12];
        } else {
          ra = rb = rc = rd = make_float4(0.f, 0.f, 0.f, 0.f);
        }
        float p0 = pdot(t00, t01, t02, t03, ra, rb, rc, rd);
        float p1 = pdot(t10, t11, t12, t13, ra, rb, rc, rd);
        float p2 = pdot(t20, t21, t22, t23, ra, rb, rc, rd);
        float p3 = pdot(t30, t31, t32, t33, ra, rb, rc, rd);
        float v = xpose_reduce4(p0, p1, p2, p3, tx);
        int ox = u - tx;  // lane tx owns pixel tx
        if ((unsigned)ox < 25u) cc[tx][oy * 25 + ox] = v;
      }
    }
    __syncthreads();

    // --- phase 2: softmax expectation, wave w -> pixel w
    {
      float vv[10];
      float lmax = -3e38f;
#pragma unroll
      for (int it = 0; it < 10; ++it) {
        int o = lane + it * 64;
        float v = (o < 625) ? cc[w][o] : -3e38f;
        vv[it] = v;
        lmax = fmaxf(lmax, v);
      }
#pragma unroll
      for (int o = 32; o; o >>= 1) lmax = fmaxf(lmax, __shfl_down(lmax, o));
      float m = __shfl(lmax, 0);
      float s = 0.f, sx = 0.f, sy = 0.f;
#pragma unroll
      for (int it = 0; it < 10; ++it) {
        int o = lane + it * 64;
        int oy = o / 25, ox = o - oy * 25;
        float e = __expf(vv[it] - m);
        s += e;
        sx += e * (float)(ox - 12);
        sy += e * (float)(oy - 12);
      }
#pragma unroll
      for (int o = 32; o; o >>= 1) {
        s += __shfl_down(s, o);
        sx += __shfl_down(sx, o);
        sy += __shfl_down(sy, o);
      }
      if (lane == 0) {
        float ox_ = 2.f * sx / s, oy_ = 2.f * sy / s;
        offs[w][0] = ox_;
        offs[w][1] = oy_;
        int pix = y * 64 + x0 + 2 * w;
        off[pix * 2 + 0] = ox_;
        off[pix * 2 + 1] = oy_;
      }
    }
    __syncthreads();

    // --- phase 3: deformed 14x14 dot grids (4 px x 196), reuse cc as D
    float(*D)[196] = (float(*)[196]) & cc[0][0];
#pragma unroll 1
    for (int r = 0; r < 13; ++r) {
      int s3 = g + (r << 6);
      if (s3 < 784) {
        int p = s3 / 196;
        int idx = s3 - p * 196;
        int a = idx / 14, b2 = idx - a * 14;
        float offx = offs[p][0], offy = offs[p][1];
        int px = x0 + 2 * p;
        int iy0 = y + (int)floorf(offy), ix0 = px + (int)floorf(offx);
        int ry = iy0 - 6 + a, rx = ix0 - 6 + b2;
        float v = 0.f;
        if ((unsigned)ry < 64u && (unsigned)rx < 64u) {
          const float4* tq = (const float4*)&tT[(y * 64 + px) * 64];
          v = qdot(tq[tx], tq[tx + 4], tq[tx + 8], tq[tx + 12],
                   &rT[(ry * 64 + rx) * 64], tx);
        }
        if (tx == 0) D[p][idx] = v;
      }
    }
    __syncthreads();

    // --- phase 4: gaussian softmax + grid for ref0, wave w -> pixel w
    {
      int px = x0 + 2 * w;
      int pix = y * 64 + px;
      float offx = offs[w][0], offy = offs[w][1];
      float fy = floorf(offy), fx = floorf(offx);
      float wy = offy - fy, wx = offx - fx;
      float w00 = (1.f - wy) * (1.f - wx), w01 = (1.f - wy) * wx;
      float w10 = wy * (1.f - wx), w11 = wy * wx;
      float sc[3];
      float lmax = -3e38f;
#pragma unroll
      for (int it = 0; it < 3; ++it) {
        int o = lane + it * 64;
        float scv = -3e38f;
        if (o < 169) {
          int i = o / 13, j = o - i * 13;
          float v = w00 * D[w][i * 14 + j] + w01 * D[w][i * 14 + j + 1] +
                    w10 * D[w][(i + 1) * 14 + j] +
                    w11 * D[w][(i + 1) * 14 + j + 1];
          float di = (float)((i - 6) * (i - 6) + (j - 6) * (j - 6));
          scv = 50.f * __expf(-0.5f * di) * v;
        }
        sc[it] = scv;
        lmax = fmaxf(lmax, scv);
      }
#pragma unroll
      for (int o = 32; o; o >>= 1) lmax = fmaxf(lmax, __shfl_down(lmax, o));
      float m = __shfl(lmax, 0);
      float ee[3];
      float s = 0.f, gx = 0.f, gy = 0.f;
#pragma unroll
      for (int it = 0; it < 3; ++it) {
        int o = lane + it * 64;
        int i = o / 13, j = o - i * 13;
        float e = __expf(sc[it] - m);
        ee[it] = e;
        int yy = y + i - 6, xx = px + j - 6;
        bool inb = (o < 169) && (unsigned)yy < 64u && (unsigned)xx < 64u;
        float xgv = inb ? (-1.f + (2.f / 63.f) * (float)xx) : 0.f;
        float ygv = inb ? (-1.f + (2.f / 63.f) * (float)yy) : 0.f;
        s += e;
        gx += e * xgv;
        gy += e * ygv;
      }
#pragma unroll
      for (int o = 32; o; o >>= 1) {
        s += __shfl_down(s, o);
        gx += __shfl_down(gx, o);
        gy += __shfl_down(gy, o);
      }
      float S = __shfl(s, 0);
#pragma unroll
      for (int it = 0; it < 3; ++it) {
        int o = lane + it * 64;
        if (o < 169) corrws[pix * 169 + o] = ee[it] / S;
      }
      if (lane == 0) {
        grid[pix * 2 + 0] = gx / S;
        grid[pix * 2 + 1] = gy / S;
      }
    }
  } else {
    // ---- refs 1,2: 4 consecutive pixels, 13x16 union ----
    int k = z;
    int x0 = xg * 4;
    const float* rb0 = rT + k * (64 * NPIX);
    LOADT(0, x0 + 0) LOADT(1, x0 + 1) LOADT(2, x0 + 2) LOADT(3, x0 + 3)
    float(*cc2)[169] = (float(*)[169]) & cc[0][0];

#pragma unroll 2
    for (int r = 0; r < 4; ++r) {
      int tu = g + (r << 6);
      if (tu < 208) {
        int i = tu >> 4, u = tu & 15;
        int ry = y + i - 6, rx = x0 - 6 + u;
        float4 ra, rbv, rc, rd;
        if ((unsigned)ry < 64u && (unsigned)rx < 64u) {
          const float4* rp = (const float4*)&rb0[(ry * 64 + rx) * 64];
          ra = rp[tx]; rbv = rp[tx + 4]; rc = rp[tx + 8]; rd = rp[tx + 12];
        } else {
          ra = rbv = rc = rd = make_float4(0.f, 0.f, 0.f, 0.f);
        }
        float p0 = pdot(t00, t01, t02, t03, ra, rbv, rc, rd);
        float p1 = pdot(t10, t11, t12, t13, ra, rbv, rc, rd);
        float p2 = pdot(t20, t21, t22, t23, ra, rbv, rc, rd);
        float p3 = pdot(t30, t31, t32, t33, ra, rbv, rc, rd);
        float v = xpose_reduce4(p0, p1, p2, p3, tx);
        int j = u - tx;  // lane tx owns pixel tx
        if ((unsigned)j < 13u) cc2[tx][i * 13 + j] = v;
      }
    }
    __syncthreads();

    // softmax + grid, wave w -> pixel w
    int px = x0 + w;
    int pix = y * 64 + px;
    float sc[3];
    float lmax = -3e38f;
#pragma unroll
    for (int it = 0; it < 3; ++it) {
      int o = lane + it * 64;
      float scv = -3e38f;
      if (o < 169) {
        int i = o / 13, j = o - i * 13;
        float di = (float)((i - 6) * (i - 6) + (j - 6) * (j - 6));
        scv = 50.f * __expf(-0.5f * di) * cc2[w][o];
      }
      sc[it] = scv;
      lmax = fmaxf(lmax, scv);
    }
#pragma unroll
    for (int o = 32; o; o >>= 1) lmax = fmaxf(lmax, __shfl_down(lmax, o));
    float m = __shfl(lmax, 0);
    float ee[3];
    float s = 0.f, gx = 0.f, gy = 0.f;
#pragma unroll
    for (int it = 0; it < 3; ++it) {
      int o = lane + it * 64;
      int i = o / 13, j = o - i * 13;
      float e = __expf(sc[it] - m);
      ee[it] = e;
      int yy = y + i - 6, xx = px + j - 6;
      bool inb = (o < 169) && (unsigned)yy < 64u && (unsigned)xx < 64u;
      float xgv = inb ? (-1.f + (2.f / 63.f) * (float)xx) : 0.f;
      float ygv = inb ? (-1.f + (2.f / 63.f) * (float)yy) : 0.f;
      s += e;
      gx += e * xgv;
      gy += e * ygv;
    }
#pragma unroll
    for (int o = 32; o; o >>= 1) {
      s += __shfl_down(s, o);
      gx += __shfl_down(gx, o);
      gy += __shfl_down(gy, o);
    }
    float S = __shfl(s, 0);
#pragma unroll
    for (int it = 0; it < 3; ++it) {
      int o = lane + it * 64;
      if (o < 169) corrws[(k * NPIX + pix) * 169 + o] = ee[it] / S;
    }
    if (lane == 0) {
      grid[(k * NPIX + pix) * 2 + 0] = gx / S;
      grid[(k * NPIX + pix) * 2 + 1] = gy / S;
    }
  }
}

// ---------------------------------------------------------------------------
// K3: out[c,pix] via per-pixel 32-bin LDS histogram. Ref0 uses the inverse
// bilinear factorization: each of the 196 grid positions gets one label load
// and one atomicAdd with the 4-tap-combined weight.
__global__ __launch_bounds__(256) void k_out(const float* __restrict__ corrws,
                                             const float* __restrict__ off,
                                             const int* __restrict__ q,
                                             float* __restrict__ out) {
  int tid = threadIdx.x;
  int pix0 = blockIdx.x * 8;
  __shared__ float bins[8][32];
  __shared__ float cr[8][169];
  __shared__ float offs[8][2];
  bins[tid >> 5][tid & 31] = 0.f;
  if (tid < 16) offs[tid >> 1][tid & 1] = off[(pix0 + (tid >> 1)) * 2 + (tid & 1)];
  for (int i = tid; i < 8 * 169; i += 256) {
    int g = i / 169, n = i - g * 169;
    cr[g][n] = corrws[(pix0 + g) * 169 + n];
  }
  __syncthreads();

  // ref0: 8 pixels x 196 grid positions
  for (int s = tid; s < 8 * 196; s += 256) {
    int g = s / 196, m = s - g * 196;
    int a = m / 14, b = m - a * 14;
    int pix = pix0 + g, y = pix >> 6, x = pix & 63;
    float offx = offs[g][0], offy = offs[g][1];
    float fy = floorf(offy), fx = floorf(offx);
    float wy = offy - fy, wx = offx - fx;
    int ry = y + (int)fy - 6 + a, rx = x + (int)fx - 6 + b;
    if ((unsigned)ry < 64u && (unsigned)rx < 64u) {
      float w00 = (1.f - wy) * (1.f - wx), w01 = (1.f - wy) * wx;
      float w10 = wy * (1.f - wx), w11 = wy * wx;
      float wgt = 0.f;
      if (a < 13) {
        if (b < 13) wgt = fmaf(w00, cr[g][a * 13 + b], wgt);
        if (b > 0) wgt = fmaf(w01, cr[g][a * 13 + b - 1], wgt);
      }
      if (a > 0) {
        if (b < 13) wgt = fmaf(w10, cr[g][(a - 1) * 13 + b], wgt);
        if (b > 0) wgt = fmaf(w11, cr[g][(a - 1) * 13 + b - 1], wgt);
      }
      if (wgt != 0.f) {
        int lbl = q[ry * 1024 + rx * 4];
        atomicAdd(&bins[g][lbl], wgt);
      }
    }
  }

  // refs 1,2: integer taps
  for (int k = 1; k < 3; ++k) {
    __syncthreads();
    for (int i = tid; i < 8 * 169; i += 256) {
      int g = i / 169, n = i - g * 169;
      cr[g][n] = corrws[((k << 12) + pix0 + g) * 169 + n];
    }
    __syncthreads();
    for (int s = tid; s < 8 * 169; s += 256) {
      int g = s / 169, n = s - g * 169;
      int i2 = n / 13, j2 = n - i2 * 13;
      int pix = pix0 + g, y = pix >> 6, x = pix & 63;
      int yy = y + i2 - 6, xx = x + j2 - 6;
      if ((unsigned)yy < 64u && (unsigned)xx < 64u) {
        int lbl = q[k * 65536 + yy * 1024 + xx * 4];
        atomicAdd(&bins[g][lbl], cr[g][n]);
      }
    }
  }
  __syncthreads();
  out[(tid >> 3) * NPIX + pix0 + (tid & 7)] = bins[tid & 7][tid >> 3];
}

// ---------------------------------------------------------------------------
extern "C" void kernel_launch(void* const* d_in, const int* in_sizes, int n_in,
                              void* d_out, int out_size, void* d_ws,
                              size_t ws_size, hipStream_t stream) {
  const float* fr = (const float*)d_in[0];  // feats_r (3,1,64,64,64)
  const float* ft = (const float*)d_in[1];  // feats_t (1,64,64,64)
  const int* q = (const int*)d_in[2];       // quantized_r (3,1,1,256,256)
  float* out = (float*)d_out;               // 131072 + 24576 floats
  float* grid = out + 32 * NPIX;

  float* ws = (float*)d_ws;
  float* tT = ws;                  // 4096*64
  float* rT = ws + 262144;         // 3*4096*64
  float* off = ws + 1048576;       // 4096*2
  float* corrws = ws + 1056768;    // 3*4096*169

  k_transpose<<<dim3(64, 4), 256, 0, stream>>>(ft, fr, tT, rT);
  k_corr_all<<<dim3(16, 64, 3), 256, 0, stream>>>(tT, rT, off, corrws, grid);
  k_out<<<512, 256, 0, stream>>>(corrws, off, q, out);
}

// Round 6
// 60.691 us; speedup vs baseline: 6.2426x; 1.0124x over previous
//
#include <hip/hip_runtime.h>

// Problem constants (fixed inputs: ref_index=[0,1,2], current_ind=16)
// -> nsearch=1, dirates=[2], nref=3
// feats_r: (3,1,64,64,64) f32, feats_t: (1,64,64,64) f32,
// quantized_r: (3,1,1,256,256) i32
// out: (1,32,64,64) f32 then grid: (3,64,64,2) f32

#define NPIX 4096   // 64*64

// 16-channel partial dot (this lane's quarter of the 64-ch dot).
__device__ __forceinline__ float pdot(float4 t0, float4 t1, float4 t2,
                                      float4 t3, float4 a, float4 b, float4 c,
                                      float4 d) {
  float s0 = 0.f, s1 = 0.f, s2 = 0.f, s3 = 0.f;
  s0 = fmaf(t0.x, a.x, s0); s1 = fmaf(t0.y, a.y, s1);
  s2 = fmaf(t0.z, a.z, s2); s3 = fmaf(t0.w, a.w, s3);
  s0 = fmaf(t1.x, b.x, s0); s1 = fmaf(t1.y, b.y, s1);
  s2 = fmaf(t1.z, b.z, s2); s3 = fmaf(t1.w, b.w, s3);
  s0 = fmaf(t2.x, c.x, s0); s1 = fmaf(t2.y, c.y, s1);
  s2 = fmaf(t2.z, c.z, s2); s3 = fmaf(t2.w, c.w, s3);
  s0 = fmaf(t3.x, d.x, s0); s1 = fmaf(t3.y, d.y, s1);
  s2 = fmaf(t3.z, d.z, s2); s3 = fmaf(t3.w, d.w, s3);
  return (s0 + s1) + (s2 + s3);
}

// 4-lane transpose-reduce: input p0..p3 = this lane's 16-ch partials for
// pixels 0..3; output: lane tx holds the full 64-ch dot of pixel tx.
__device__ __forceinline__ float xpose_reduce4(float p0, float p1, float p2,
                                               float p3, int tx) {
  bool o1 = tx & 1, o2 = tx & 2;
  float x01 = __shfl_xor(o1 ? p0 : p1, 1);
  float x23 = __shfl_xor(o1 ? p2 : p3, 1);
  float sA = (o1 ? p1 : p0) + x01;
  float sB = (o1 ? p3 : p2) + x23;
  float z = __shfl_xor(o2 ? sA : sB, 2);
  return o2 ? (sB + z) : (sA + z);
}

// ---------------------------------------------------------------------------
// K0: transpose [c][pix] -> [pix][c] for feats_t and the 3 feats_r refs,
// and pack the (::4,::4) label planes into dense uchar[3][4096].
__global__ __launch_bounds__(256) void k_transpose(
    const float* __restrict__ ft, const float* __restrict__ fr,
    const int* __restrict__ q, float* __restrict__ tT, float* __restrict__ rT,
    unsigned char* __restrict__ lblp) {
  __shared__ float tile[64][65];
  int img = blockIdx.y;
  int pixBase = blockIdx.x * 64;
  const float* src = (img == 0) ? ft : fr + (img - 1) * (64 * NPIX);
  float* dst = (img == 0) ? tT : rT + (img - 1) * (64 * NPIX);
  int tid = threadIdx.x;
#pragma unroll
  for (int it = 0; it < 16; ++it) {
    int li = it * 256 + tid;
    int c = li >> 6, p = li & 63;
    tile[p][c] = src[c * NPIX + pixBase + p];
  }
  __syncthreads();
#pragma unroll
  for (int it = 0; it < 16; ++it) {
    int li = it * 256 + tid;
    int p = li >> 6, c = li & 63;
    dst[(pixBase + p) * 64 + c] = tile[p][c];
  }
  if (img >= 1 && tid < 64) {
    int pix = pixBase + tid;
    lblp[(img - 1) * 4096 + pix] =
        (unsigned char)q[(img - 1) * 65536 + (pix >> 6) * 1024 + (pix & 63) * 4];
  }
}

// t-fragment loader: 16 ch (4 float4) of pixel (row y, col xc) into 4 regs.
#define LOADT(N, XC)                                                       \
  const float4* tp##N = (const float4*)&tT[((y << 6) + (XC)) << 6];        \
  float4 t##N##0 = tp##N[tx], t##N##1 = tp##N[tx + 4],                     \
         t##N##2 = tp##N[tx + 8], t##N##3 = tp##N[tx + 12];

// Phase-3 helper: 14x16-padded deformed dot grid for one pixel.
// Group g = (aB = g>>4, b3 = g&15); 4 rounds cover a = aB+4r in [0,16).
__device__ __forceinline__ void phase3_px(
    float4 T0, float4 T1, float4 T2, float4 T3, int iy0, int ix0,
    const float* __restrict__ rT, float* __restrict__ Dp, int aB, int b3,
    int tx) {
#pragma unroll 1
  for (int r = 0; r < 4; ++r) {
    int a = aB + 4 * r;
    int ry = iy0 + a, rx = ix0 + b3;
    bool ok = (a < 14) & (b3 < 14) & ((unsigned)ry < 64u) & ((unsigned)rx < 64u);
    int ryc = min(max(ry, 0), 63), rxc = min(max(rx, 0), 63);
    const float4* rp = (const float4*)&rT[(ryc * 64 + rxc) * 64 + tx * 4];
    float4 ra = rp[0], rb = rp[4], rc = rp[8], rd = rp[12];
    float v = pdot(T0, T1, T2, T3, ra, rb, rc, rd);
    v += __shfl_xor(v, 1);
    v += __shfl_xor(v, 2);
    v = ok ? v : 0.f;
    if ((a < 14) && (b3 < 14) && tx == 0) Dp[a * 14 + b3] = v;
  }
}

// ---------------------------------------------------------------------------
// K1: fused correlation kernel. grid (16, 64, 3), 4 pixels per block.
__global__ __launch_bounds__(256) void k_corr_all(
    const float* __restrict__ tT, const float* __restrict__ rT,
    float* __restrict__ off, float* __restrict__ corrws,
    float* __restrict__ grid) {
  int z = blockIdx.z;
  int xg = blockIdx.x, y = blockIdx.y;
  int tid = threadIdx.x;
  int g = tid >> 2, tx = tid & 3;
  int w = tid >> 6, lane = tid & 63;
  __shared__ float cc[4][625];   // 10 KB; z>=1 aliases as [4][169]
  __shared__ float offs[4][2];

  if (z == 0) {
    int x0 = (xg >> 1) * 8 + (xg & 1);  // pixels x0 + {0,2,4,6}
    LOADT(0, x0 + 0) LOADT(1, x0 + 2) LOADT(2, x0 + 4) LOADT(3, x0 + 6)

    // --- phase 1: 25x32-padded union dilated dots -> cc[4][625].
    // Per-lane constants; only ry/oy advance per round (+4/+2).
    {
      int u = g & 31;                        // union col (const)
      int rx = x0 - 24 + 2 * u;              // const
      bool col_ok = ((unsigned)rx < 64u) & (u < 28);
      int rx_c = min(max(rx, 0), 63);
      int colB = rx_c * 64 + tx * 4;         // float offset within row
      int ox = u - tx;                       // tap col for pixel tx (const)
      bool st_col = (unsigned)ox < 25u;
      int oy = g >> 5;                       // 0/1, +2 per round
      int ry = y + 2 * oy - 24;              // +4 per round
#pragma unroll 1
      for (int r = 0; r < 13; ++r) {
        bool oy_ok = oy < 25;
        bool ok = col_ok & oy_ok & ((unsigned)ry < 64u);
        int ry_c = min(max(ry, 0), 63);
        const float4* rp = (const float4*)&rT[ry_c * 4096 + colB];
        float4 ra = rp[0], rb = rp[4], rc = rp[8], rd = rp[12];
        float p0 = pdot(t00, t01, t02, t03, ra, rb, rc, rd);
        float p1 = pdot(t10, t11, t12, t13, ra, rb, rc, rd);
        float p2 = pdot(t20, t21, t22, t23, ra, rb, rc, rd);
        float p3 = pdot(t30, t31, t32, t33, ra, rb, rc, rd);
        float v = xpose_reduce4(p0, p1, p2, p3, tx);
        v = ok ? v : 0.f;
        if (st_col && oy_ok) cc[tx][oy * 25 + ox] = v;
        oy += 2;
        ry += 4;
      }
    }
    __syncthreads();

    // --- phase 2: softmax expectation, wave w -> pixel w
    {
      float vv[10];
      float lmax = -3e38f;
#pragma unroll
      for (int it = 0; it < 10; ++it) {
        int o = lane + it * 64;
        float v = (o < 625) ? cc[w][o] : -3e38f;
        vv[it] = v;
        lmax = fmaxf(lmax, v);
      }
#pragma unroll
      for (int o = 32; o; o >>= 1) lmax = fmaxf(lmax, __shfl_down(lmax, o));
      float m = __shfl(lmax, 0);
      float s = 0.f, sx = 0.f, sy = 0.f;
#pragma unroll
      for (int it = 0; it < 10; ++it) {
        int o = lane + it * 64;
        int oy = o / 25, ox = o - oy * 25;
        float e = __expf(vv[it] - m);
        s += e;
        sx += e * (float)(ox - 12);
        sy += e * (float)(oy - 12);
      }
#pragma unroll
      for (int o = 32; o; o >>= 1) {
        s += __shfl_down(s, o);
        sx += __shfl_down(sx, o);
        sy += __shfl_down(sy, o);
      }
      if (lane == 0) {
        float ox_ = 2.f * sx / s, oy_ = 2.f * sy / s;
        offs[w][0] = ox_;
        offs[w][1] = oy_;
        int pix = y * 64 + x0 + 2 * w;
        off[pix * 2 + 0] = ox_;
        off[pix * 2 + 1] = oy_;
      }
    }
    __syncthreads();   // phase-2 reads of cc done before D overwrites it

    // --- phase 3: deformed 14x14 dot grids (t-fragments reused in-register)
    float(*D)[196] = (float(*)[196]) & cc[0][0];
    {
      int b3 = g & 15, aB = g >> 4;
      {
        float offx = offs[0][0], offy = offs[0][1];
        phase3_px(t00, t01, t02, t03, y + (int)floorf(offy) - 6,
                  x0 + 0 + (int)floorf(offx) - 6, rT, &D[0][0], aB, b3, tx);
      }
      {
        float offx = offs[1][0], offy = offs[1][1];
        phase3_px(t10, t11, t12, t13, y + (int)floorf(offy) - 6,
                  x0 + 2 + (int)floorf(offx) - 6, rT, &D[1][0], aB, b3, tx);
      }
      {
        float offx = offs[2][0], offy = offs[2][1];
        phase3_px(t20, t21, t22, t23, y + (int)floorf(offy) - 6,
                  x0 + 4 + (int)floorf(offx) - 6, rT, &D[2][0], aB, b3, tx);
      }
      {
        float offx = offs[3][0], offy = offs[3][1];
        phase3_px(t30, t31, t32, t33, y + (int)floorf(offy) - 6,
                  x0 + 6 + (int)floorf(offx) - 6, rT, &D[3][0], aB, b3, tx);
      }
    }
    __syncthreads();

    // --- phase 4: gaussian softmax + grid for ref0, wave w -> pixel w
    {
      int px = x0 + 2 * w;
      int pix = y * 64 + px;
      float offx = offs[w][0], offy = offs[w][1];
      float fy = floorf(offy), fx = floorf(offx);
      float wy = offy - fy, wx = offx - fx;
      float w00 = (1.f - wy) * (1.f - wx), w01 = (1.f - wy) * wx;
      float w10 = wy * (1.f - wx), w11 = wy * wx;
      float sc[3];
      float lmax = -3e38f;
#pragma unroll
      for (int it = 0; it < 3; ++it) {
        int o = lane + it * 64;
        float scv = -3e38f;
        if (o < 169) {
          int i = o / 13, j = o - i * 13;
          float v = w00 * D[w][i * 14 + j] + w01 * D[w][i * 14 + j + 1] +
                    w10 * D[w][(i + 1) * 14 + j] +
                    w11 * D[w][(i + 1) * 14 + j + 1];
          float di = (float)((i - 6) * (i - 6) + (j - 6) * (j - 6));
          scv = 50.f * __expf(-0.5f * di) * v;
        }
        sc[it] = scv;
        lmax = fmaxf(lmax, scv);
      }
#pragma unroll
      for (int o = 32; o; o >>= 1) lmax = fmaxf(lmax, __shfl_down(lmax, o));
      float m = __shfl(lmax, 0);
      float ee[3];
      float s = 0.f, gx = 0.f, gy = 0.f;
#pragma unroll
      for (int it = 0; it < 3; ++it) {
        int o = lane + it * 64;
        int i = o / 13, j = o - i * 13;
        float e = __expf(sc[it] - m);
        ee[it] = e;
        int yy = y + i - 6, xx = px + j - 6;
        bool inb = (o < 169) && (unsigned)yy < 64u && (unsigned)xx < 64u;
        float xgv = inb ? (-1.f + (2.f / 63.f) * (float)xx) : 0.f;
        float ygv = inb ? (-1.f + (2.f / 63.f) * (float)yy) : 0.f;
        s += e;
        gx += e * xgv;
        gy += e * ygv;
      }
#pragma unroll
      for (int o = 32; o; o >>= 1) {
        s += __shfl_down(s, o);
        gx += __shfl_down(gx, o);
        gy += __shfl_down(gy, o);
      }
      float S = __shfl(s, 0);
#pragma unroll
      for (int it = 0; it < 3; ++it) {
        int o = lane + it * 64;
        if (o < 169) corrws[pix * 169 + o] = ee[it] / S;
      }
      if (lane == 0) {
        grid[pix * 2 + 0] = gx / S;
        grid[pix * 2 + 1] = gy / S;
      }
    }
  } else {
    // ---- refs 1,2: 4 consecutive pixels, exact 13x16 union ----
    int k = z;
    int x0 = xg * 4;
    const float* rb0 = rT + k * (64 * NPIX);
    LOADT(0, x0 + 0) LOADT(1, x0 + 1) LOADT(2, x0 + 2) LOADT(3, x0 + 3)
    float(*cc2)[169] = (float(*)[169]) & cc[0][0];

    {
      int u2 = g & 15;                      // const
      int rx = x0 - 6 + u2;                 // const
      bool col_ok = (unsigned)rx < 64u;
      int rx_c = min(max(rx, 0), 63);
      int colB = rx_c * 64 + tx * 4;
      int j = u2 - tx;                      // const
      bool st_col = (unsigned)j < 13u;
      int i = g >> 4;                       // +4 per round
      int ry = y + i - 6;                   // +4 per round
#pragma unroll 1
      for (int r = 0; r < 4; ++r) {
        bool i_ok = i < 13;
        bool ok = col_ok & i_ok & ((unsigned)ry < 64u);
        int ry_c = min(max(ry, 0), 63);
        const float4* rp = (const float4*)&rb0[ry_c * 4096 + colB];
        float4 ra = rp[0], rbv = rp[4], rc = rp[8], rd = rp[12];
        float p0 = pdot(t00, t01, t02, t03, ra, rbv, rc, rd);
        float p1 = pdot(t10, t11, t12, t13, ra, rbv, rc, rd);
        float p2 = pdot(t20, t21, t22, t23, ra, rbv, rc, rd);
        float p3 = pdot(t30, t31, t32, t33, ra, rbv, rc, rd);
        float v = xpose_reduce4(p0, p1, p2, p3, tx);
        v = ok ? v : 0.f;
        if (st_col && i_ok) cc2[tx][i * 13 + j] = v;
        i += 4;
        ry += 4;
      }
    }
    __syncthreads();

    // softmax + grid, wave w -> pixel w
    int px = x0 + w;
    int pix = y * 64 + px;
    float sc[3];
    float lmax = -3e38f;
#pragma unroll
    for (int it = 0; it < 3; ++it) {
      int o = lane + it * 64;
      float scv = -3e38f;
      if (o < 169) {
        int i = o / 13, j = o - i * 13;
        float di = (float)((i - 6) * (i - 6) + (j - 6) * (j - 6));
        scv = 50.f * __expf(-0.5f * di) * cc2[w][o];
      }
      sc[it] = scv;
      lmax = fmaxf(lmax, scv);
    }
#pragma unroll
    for (int o = 32; o; o >>= 1) lmax = fmaxf(lmax, __shfl_down(lmax, o));
    float m = __shfl(lmax, 0);
    float ee[3];
    float s = 0.f, gx = 0.f, gy = 0.f;
#pragma unroll
    for (int it = 0; it < 3; ++it) {
      int o = lane + it * 64;
      int i = o / 13, j = o - i * 13;
      float e = __expf(sc[it] - m);
      ee[it] = e;
      int yy = y + i - 6, xx = px + j - 6;
      bool inb = (o < 169) && (unsigned)yy < 64u && (unsigned)xx < 64u;
      float xgv = inb ? (-1.f + (2.f / 63.f) * (float)xx) : 0.f;
      float ygv = inb ? (-1.f + (2.f / 63.f) * (float)yy) : 0.f;
      s += e;
      gx += e * xgv;
      gy += e * ygv;
    }
#pragma unroll
    for (int o = 32; o; o >>= 1) {
      s += __shfl_down(s, o);
      gx += __shfl_down(gx, o);
      gy += __shfl_down(gy, o);
    }
    float S = __shfl(s, 0);
#pragma unroll
    for (int it = 0; it < 3; ++it) {
      int o = lane + it * 64;
      if (o < 169) corrws[(k * NPIX + pix) * 169 + o] = ee[it] / S;
    }
    if (lane == 0) {
      grid[(k * NPIX + pix) * 2 + 0] = gx / S;
      grid[(k * NPIX + pix) * 2 + 1] = gy / S;
    }
  }
}

// ---------------------------------------------------------------------------
// K3: out[c,pix] via per-pixel 33-padded LDS histogram; labels staged to LDS
// from the dense packed planes; per-px bilinear constants hoisted.
__global__ __launch_bounds__(256) void k_out(
    const float* __restrict__ corrws, const float* __restrict__ off,
    const unsigned char* __restrict__ lblp, float* __restrict__ out) {
  int tid = threadIdx.x;
  int pix0 = blockIdx.x * 8;
  __shared__ float bins[8][33];
  __shared__ float cr[8][169];
  __shared__ __align__(16) unsigned char lbl[3 * 4096];
  __shared__ float w4[8][4];
  __shared__ int bse[8][2];

  for (int i = tid; i < 264; i += 256) ((float*)bins)[i] = 0.f;
  for (int i = tid; i < 768; i += 256)
    ((int4*)lbl)[i] = ((const int4*)lblp)[i];
  for (int i = tid; i < 1352; i += 256) {
    int g2 = i / 169, n = i - g2 * 169;
    cr[g2][n] = corrws[(pix0 + g2) * 169 + n];
  }
  if (tid < 8) {
    float offx = off[(pix0 + tid) * 2 + 0], offy = off[(pix0 + tid) * 2 + 1];
    float fy = floorf(offy), fx = floorf(offx);
    float wy = offy - fy, wx = offx - fx;
    w4[tid][0] = (1.f - wy) * (1.f - wx);
    w4[tid][1] = (1.f - wy) * wx;
    w4[tid][2] = wy * (1.f - wx);
    w4[tid][3] = wy * wx;
    int pix = pix0 + tid;
    bse[tid][0] = (pix >> 6) + (int)fy - 6;
    bse[tid][1] = (pix & 63) + (int)fx - 6;
  }
  __syncthreads();

  // ref0: px-outer; thread = (a = tid>>4 in [0,14), b = tid&15, b<14 active)
  {
    int a = tid >> 4, b = tid & 15;
    bool act0 = (tid < 224) && (b < 14);
#pragma unroll 1
    for (int p = 0; p < 8; ++p) {
      if (act0) {
        int ry = bse[p][0] + a, rx = bse[p][1] + b;
        if ((unsigned)ry < 64u && (unsigned)rx < 64u) {
          float wgt = 0.f;
          const float* crp = cr[p];
          if (a < 13) {
            if (b < 13) wgt = fmaf(w4[p][0], crp[a * 13 + b], wgt);
            if (b > 0) wgt = fmaf(w4[p][1], crp[a * 13 + b - 1], wgt);
          }
          if (a > 0) {
            if (b < 13) wgt = fmaf(w4[p][2], crp[(a - 1) * 13 + b], wgt);
            if (b > 0) wgt = fmaf(w4[p][3], crp[(a - 1) * 13 + b - 1], wgt);
          }
          if (wgt != 0.f) atomicAdd(&bins[p][lbl[ry * 64 + rx]], wgt);
        }
      }
    }
  }

  // refs 1,2: thread = (i2 = tid>>4 in [0,13), j2 = tid&15, j2<13 active)
  {
    int i2 = tid >> 4, j2 = tid & 15;
    bool act12 = (tid < 208) && (j2 < 13);
    for (int k = 1; k < 3; ++k) {
      __syncthreads();
      for (int i = tid; i < 1352; i += 256) {
        int g2 = i / 169, n = i - g2 * 169;
        cr[g2][n] = corrws[((k << 12) + pix0 + g2) * 169 + n];
      }
      __syncthreads();
#pragma unroll 1
      for (int p = 0; p < 8; ++p) {
        if (act12) {
          int pix = pix0 + p;
          int yy = (pix >> 6) + i2 - 6, xx = (pix & 63) + j2 - 6;
          if ((unsigned)yy < 64u && (unsigned)xx < 64u)
            atomicAdd(&bins[p][lbl[(k << 12) + yy * 64 + xx]],
                      cr[p][i2 * 13 + j2]);
        }
      }
    }
  }
  __syncthreads();
  out[(tid >> 3) * NPIX + pix0 + (tid & 7)] = bins[tid & 7][tid >> 3];
}

// ---------------------------------------------------------------------------
extern "C" void kernel_launch(void* const* d_in, const int* in_sizes, int n_in,
                              void* d_out, int out_size, void* d_ws,
                              size_t ws_size, hipStream_t stream) {
  const float* fr = (const float*)d_in[0];  // feats_r (3,1,64,64,64)
  const float* ft = (const float*)d_in[1];  // feats_t (1,64,64,64)
  const int* q = (const int*)d_in[2];       // quantized_r (3,1,1,256,256)
  float* out = (float*)d_out;               // 131072 + 24576 floats
  float* grid = out + 32 * NPIX;

  float* ws = (float*)d_ws;
  float* tT = ws;                              // 4096*64
  float* rT = ws + 262144;                     // 3*4096*64
  float* off = ws + 1048576;                   // 4096*2
  float* corrws = ws + 1056768;                // 3*4096*169
  unsigned char* lblp = (unsigned char*)(ws + 3133440);  // 3*4096 uchar

  k_transpose<<<dim3(64, 4), 256, 0, stream>>>(ft, fr, q, tT, rT, lblp);
  k_corr_all<<<dim3(16, 64, 3), 256, 0, stream>>>(tT, rT, off, corrws, grid);
  k_out<<<512, 256, 0, stream>>>(corrws, off, lblp, out);
}

// Round 7
// 58.958 us; speedup vs baseline: 6.4262x; 1.0294x over previous
//
#include <hip/hip_runtime.h>

// Problem constants (fixed inputs: ref_index=[0,1,2], current_ind=16)
// -> nsearch=1, dirates=[2], nref=3
// feats_r: (3,1,64,64,64) f32, feats_t: (1,64,64,64) f32,
// quantized_r: (3,1,1,256,256) i32
// out: (1,32,64,64) f32 then grid: (3,64,64,2) f32

#define NPIX 4096   // 64*64

// 16-channel partial dot (this lane's quarter of the 64-ch dot).
__device__ __forceinline__ float pdot(float4 t0, float4 t1, float4 t2,
                                      float4 t3, float4 a, float4 b, float4 c,
                                      float4 d) {
  float s0 = 0.f, s1 = 0.f, s2 = 0.f, s3 = 0.f;
  s0 = fmaf(t0.x, a.x, s0); s1 = fmaf(t0.y, a.y, s1);
  s2 = fmaf(t0.z, a.z, s2); s3 = fmaf(t0.w, a.w, s3);
  s0 = fmaf(t1.x, b.x, s0); s1 = fmaf(t1.y, b.y, s1);
  s2 = fmaf(t1.z, b.z, s2); s3 = fmaf(t1.w, b.w, s3);
  s0 = fmaf(t2.x, c.x, s0); s1 = fmaf(t2.y, c.y, s1);
  s2 = fmaf(t2.z, c.z, s2); s3 = fmaf(t2.w, c.w, s3);
  s0 = fmaf(t3.x, d.x, s0); s1 = fmaf(t3.y, d.y, s1);
  s2 = fmaf(t3.z, d.z, s2); s3 = fmaf(t3.w, d.w, s3);
  return (s0 + s1) + (s2 + s3);
}

// 4-lane cooperative full dot (all 4 lanes get the result).
__device__ __forceinline__ float qdot(float4 ta, float4 tb, float4 tc,
                                      float4 td,
                                      const float* __restrict__ rbase,
                                      int tx) {
  const float4* r = (const float4*)rbase;
  float v = pdot(ta, tb, tc, td, r[tx], r[tx + 4], r[tx + 8], r[tx + 12]);
  v += __shfl_xor(v, 1);
  v += __shfl_xor(v, 2);
  return v;
}

// 4-lane transpose-reduce: p0..p3 = this lane's 16-ch partials for pixels
// 0..3; result: lane tx holds the full 64-ch dot of pixel tx.
__device__ __forceinline__ float xpose_reduce4(float p0, float p1, float p2,
                                               float p3, int tx) {
  bool o1 = tx & 1, o2 = tx & 2;
  float x01 = __shfl_xor(o1 ? p0 : p1, 1);
  float x23 = __shfl_xor(o1 ? p2 : p3, 1);
  float sA = (o1 ? p1 : p0) + x01;
  float sB = (o1 ? p3 : p2) + x23;
  float z = __shfl_xor(o2 ? sA : sB, 2);
  return o2 ? (sB + z) : (sA + z);
}

// ---------------------------------------------------------------------------
// K0: transpose [c][pix] -> [pix][c] (float4 both sides via LDS tile) and
// pack the (::4,::4) label planes into dense uchar[3][4096].
__global__ __launch_bounds__(256) void k_transpose(
    const float* __restrict__ ft, const float* __restrict__ fr,
    const int* __restrict__ q, float* __restrict__ tT, float* __restrict__ rT,
    unsigned char* __restrict__ lblp) {
  __shared__ float tile[64][65];
  int img = blockIdx.y;
  int pixBase = blockIdx.x * 64;
  const float* src = (img == 0) ? ft : fr + (img - 1) * (64 * NPIX);
  float* dst = (img == 0) ? tT : rT + (img - 1) * (64 * NPIX);
  int tid = threadIdx.x;
#pragma unroll
  for (int it = 0; it < 4; ++it) {
    int idx = it * 256 + tid;        // 0..1023
    int c = idx >> 4;                // channel
    int p4 = (idx & 15) << 2;        // pixel group of 4
    float4 v = *(const float4*)&src[c * NPIX + pixBase + p4];
    tile[p4 + 0][c] = v.x;
    tile[p4 + 1][c] = v.y;
    tile[p4 + 2][c] = v.z;
    tile[p4 + 3][c] = v.w;
  }
  __syncthreads();
#pragma unroll
  for (int it = 0; it < 4; ++it) {
    int idx = it * 256 + tid;
    int p = idx >> 4;
    int c4 = (idx & 15) << 2;
    float4 v = make_float4(tile[p][c4], tile[p][c4 + 1], tile[p][c4 + 2],
                           tile[p][c4 + 3]);
    *(float4*)&dst[(pixBase + p) * 64 + c4] = v;
  }
  if (img >= 1 && tid < 64) {
    int pix = pixBase + tid;
    lblp[(img - 1) * 4096 + pix] = (unsigned char)
        q[(img - 1) * 65536 + (pix >> 6) * 1024 + (pix & 63) * 4];
  }
}

// t-fragment loader: 16 ch (4 float4) of pixel (row y, col xc) into 4 regs.
#define LOADT(N, XC)                                                       \
  const float4* tp##N = (const float4*)&tT[((y << 6) + (XC)) << 6];        \
  float4 t##N##0 = tp##N[tx], t##N##1 = tp##N[tx + 4],                     \
         t##N##2 = tp##N[tx + 8], t##N##3 = tp##N[tx + 12];

// Phase-3 helper: 14x14 deformed dot grid for pixel P (196 positions,
// 4 rounds of 64 groups, linear layout with guard).
#define PH3(P, T0, T1, T2, T3)                                             \
  {                                                                        \
    float offx = offs[P][0], offy = offs[P][1];                            \
    int iy0 = y + (int)floorf(offy) - 6;                                   \
    int ix0 = x0 + 2 * (P) + (int)floorf(offx) - 6;                        \
    _Pragma("unroll 2") for (int r = 0; r < 4; ++r) {                      \
      int s = g + (r << 6);                                                \
      int a = s / 14, b = s - a * 14;                                      \
      int ry = iy0 + a, rx = ix0 + b;                                      \
      bool ok = (s < 196) & ((unsigned)ry < 64u) & ((unsigned)rx < 64u);   \
      int ryc = min(max(ry, 0), 63), rxc = min(max(rx, 0), 63);            \
      float v = qdot(T0, T1, T2, T3, &rT[(ryc * 64 + rxc) * 64], tx);      \
      v = ok ? v : 0.f;                                                    \
      if ((s < 196) && tx == 0) ccf[(P) * 196 + s] = v;                    \
    }                                                                      \
  }

// ---------------------------------------------------------------------------
// K1: fully fused per-pixel-group kernel. grid (16, 64); block owns 4
// stride-2 pixels {x0, x0+2, x0+4, x0+6} of row y and produces out+grid.
__global__ __launch_bounds__(256) void k_fused(
    const float* __restrict__ tT, const float* __restrict__ rT,
    const unsigned char* __restrict__ lblp, float* __restrict__ out,
    float* __restrict__ grid) {
  int xg = blockIdx.x, y = blockIdx.y;
  int x0 = (xg >> 1) * 8 + (xg & 1);  // pixels x0 + {0,2,4,6}
  int tid = threadIdx.x;
  int g = tid >> 2, tx = tid & 3;
  int w = tid >> 6, lane = tid & 63;
  __shared__ float ccf[2500];     // 10 KB, re-purposed per phase
  __shared__ float offs[4][2];
  __shared__ float bins[4][33];

  if (tid < 132) ((float*)bins)[tid] = 0.f;

  LOADT(0, x0 + 0) LOADT(1, x0 + 2) LOADT(2, x0 + 4) LOADT(3, x0 + 6)

  // ---- ph1: 25x32-padded union dilated dots -> ccf[px*625 + oy*25+ox],
  // software-pipelined (next round's 4 r-vectors prefetched).
  {
    int u = g & 31;
    int rx = x0 - 24 + 2 * u;
    bool col_ok = ((unsigned)rx < 64u) & (u < 28);
    int rx_c = min(max(rx, 0), 63);
    int colB = rx_c * 64 + tx * 4;
    int ox = u - tx;
    bool st_col = (unsigned)ox < 25u;
    int oy = g >> 5;
    int ry = y + 2 * oy - 24;
    int ry_c = min(max(ry, 0), 63);
    const float4* rp = (const float4*)&rT[ry_c * 4096 + colB];
    float4 ra = rp[0], rb = rp[4], rc = rp[8], rd = rp[12];
#pragma unroll 1
    for (int r = 0; r < 13; ++r) {
      int ry_n = ry + 4;
      int ryn_c = min(max(ry_n, 0), 63);
      const float4* np = (const float4*)&rT[ryn_c * 4096 + colB];
      float4 na = np[0], nb = np[4], nc = np[8], nd = np[12];
      float p0 = pdot(t00, t01, t02, t03, ra, rb, rc, rd);
      float p1 = pdot(t10, t11, t12, t13, ra, rb, rc, rd);
      float p2 = pdot(t20, t21, t22, t23, ra, rb, rc, rd);
      float p3 = pdot(t30, t31, t32, t33, ra, rb, rc, rd);
      float v = xpose_reduce4(p0, p1, p2, p3, tx);
      bool ok = col_ok & (oy < 25) & ((unsigned)ry < 64u);
      v = ok ? v : 0.f;
      if (st_col && (oy < 25)) ccf[tx * 625 + oy * 25 + ox] = v;
      oy += 2;
      ry = ry_n;
      ra = na; rb = nb; rc = nc; rd = nd;
    }
  }
  __syncthreads();

  // ---- ph2: softmax expectation, wave w -> pixel w -> offs[w]
  {
    float vv[10];
    float lmax = -3e38f;
#pragma unroll
    for (int it = 0; it < 10; ++it) {
      int o = lane + it * 64;
      float v = (o < 625) ? ccf[w * 625 + o] : -3e38f;
      vv[it] = v;
      lmax = fmaxf(lmax, v);
    }
#pragma unroll
    for (int o = 32; o; o >>= 1) lmax = fmaxf(lmax, __shfl_down(lmax, o));
    float m = __shfl(lmax, 0);
    float s = 0.f, sx = 0.f, sy = 0.f;
#pragma unroll
    for (int it = 0; it < 10; ++it) {
      int o = lane + it * 64;
      int oy = o / 25, ox = o - oy * 25;
      float e = __expf(vv[it] - m);
      s += e;
      sx += e * (float)(ox - 12);
      sy += e * (float)(oy - 12);
    }
#pragma unroll
    for (int o = 32; o; o >>= 1) {
      s += __shfl_down(s, o);
      sx += __shfl_down(sx, o);
      sy += __shfl_down(sy, o);
    }
    if (lane == 0) {
      offs[w][0] = 2.f * sx / s;
      offs[w][1] = 2.f * sy / s;
    }
  }
  __syncthreads();

  // ---- ph3: deformed 14x14 dot grids -> ccf[px*196 + s] (4 px x 4 rounds)
  PH3(0, t00, t01, t02, t03)
  PH3(1, t10, t11, t12, t13)
  PH3(2, t20, t21, t22, t23)
  PH3(3, t30, t31, t32, t33)
  __syncthreads();

  // ---- ph4: ref0 gaussian softmax (bilinear combine), wave w -> pixel w.
  // Normalized corr0 -> ccf[1024 + w*169 + o]; grid[0] written.
  {
    int px = x0 + 2 * w;
    int pix = y * 64 + px;
    float offx = offs[w][0], offy = offs[w][1];
    float fy = floorf(offy), fx = floorf(offx);
    float wy = offy - fy, wx = offx - fx;
    float w00 = (1.f - wy) * (1.f - wx), w01 = (1.f - wy) * wx;
    float w10 = wy * (1.f - wx), w11 = wy * wx;
    const float* Dw = &ccf[w * 196];
    float sc[3];
    float lmax = -3e38f;
#pragma unroll
    for (int it = 0; it < 3; ++it) {
      int o = lane + it * 64;
      float scv = -3e38f;
      if (o < 169) {
        int i = o / 13, j = o - i * 13;
        float v = w00 * Dw[i * 14 + j] + w01 * Dw[i * 14 + j + 1] +
                  w10 * Dw[(i + 1) * 14 + j] + w11 * Dw[(i + 1) * 14 + j + 1];
        float di = (float)((i - 6) * (i - 6) + (j - 6) * (j - 6));
        scv = 50.f * __expf(-0.5f * di) * v;
      }
      sc[it] = scv;
      lmax = fmaxf(lmax, scv);
    }
#pragma unroll
    for (int o = 32; o; o >>= 1) lmax = fmaxf(lmax, __shfl_down(lmax, o));
    float m = __shfl(lmax, 0);
    float ee[3];
    float s = 0.f, gx = 0.f, gy = 0.f;
#pragma unroll
    for (int it = 0; it < 3; ++it) {
      int o = lane + it * 64;
      int i = o / 13, j = o - i * 13;
      float e = __expf(sc[it] - m);
      ee[it] = e;
      int yy = y + i - 6, xx = px + j - 6;
      bool inb = (o < 169) && (unsigned)yy < 64u && (unsigned)xx < 64u;
      float xgv = inb ? (-1.f + (2.f / 63.f) * (float)xx) : 0.f;
      float ygv = inb ? (-1.f + (2.f / 63.f) * (float)yy) : 0.f;
      s += e;
      gx += e * xgv;
      gy += e * ygv;
    }
#pragma unroll
    for (int o = 32; o; o >>= 1) {
      s += __shfl_down(s, o);
      gx += __shfl_down(gx, o);
      gy += __shfl_down(gy, o);
    }
    float S = __shfl(s, 0);
    float invS = 1.f / S;
#pragma unroll
    for (int it = 0; it < 3; ++it) {
      int o = lane + it * 64;
      if (o < 169) ccf[1024 + w * 169 + o] = ee[it] * invS;
    }
    if (lane == 0) {
      grid[pix * 2 + 0] = gx * invS;
      grid[pix * 2 + 1] = gy * invS;
    }
  }
  __syncthreads();

  // ---- ph5: ref0 histogram via inverse bilinear (4 px x 196 positions)
  {
#pragma unroll 1
    for (int s = tid; s < 784; s += 256) {
      int p = s / 196, m2 = s - p * 196;
      int a = m2 / 14, b = m2 - a * 14;
      float offx = offs[p][0], offy = offs[p][1];
      float fy = floorf(offy), fx = floorf(offx);
      float wy = offy - fy, wx = offx - fx;
      int ry = y + (int)fy - 6 + a;
      int rx = x0 + 2 * p + (int)fx - 6 + b;
      if ((unsigned)ry < 64u && (unsigned)rx < 64u) {
        float w00 = (1.f - wy) * (1.f - wx), w01 = (1.f - wy) * wx;
        float w10 = wy * (1.f - wx), w11 = wy * wx;
        const float* crp = &ccf[1024 + p * 169];
        float wgt = 0.f;
        if (a < 13) {
          if (b < 13) wgt = fmaf(w00, crp[a * 13 + b], wgt);
          if (b > 0) wgt = fmaf(w01, crp[a * 13 + b - 1], wgt);
        }
        if (a > 0) {
          if (b < 13) wgt = fmaf(w10, crp[(a - 1) * 13 + b], wgt);
          if (b > 0) wgt = fmaf(w11, crp[(a - 1) * 13 + b - 1], wgt);
        }
        if (wgt != 0.f) atomicAdd(&bins[p][lblp[ry * 64 + rx]], wgt);
      }
    }
  }

  // ---- refs 1,2: union dots -> softmax (regs) -> grid + histogram
  for (int k = 1; k <= 2; ++k) {
    __syncthreads();  // prior readers of ccf[0..676) done (k=2: ph7 reads)
    const float* rb0 = rT + k * (64 * NPIX);
    // ph6: 13x19 union (247 pad 256), 4 rounds -> ccf[px*169 + i*13+j]
    {
#pragma unroll 2
      for (int r = 0; r < 4; ++r) {
        int tu = g + (r << 6);
        int i = tu / 19, u = tu - i * 19;
        int ry = y + i - 6, rx = x0 - 6 + u;
        bool ok = (i < 13) & ((unsigned)ry < 64u) & ((unsigned)rx < 64u);
        int ryc = min(max(ry, 0), 63), rxc = min(max(rx, 0), 63);
        const float4* rp = (const float4*)&rb0[(ryc * 64 + rxc) * 64 + tx * 4];
        float4 ra = rp[0], rb = rp[4], rc = rp[8], rd = rp[12];
        float p0 = pdot(t00, t01, t02, t03, ra, rb, rc, rd);
        float p1 = pdot(t10, t11, t12, t13, ra, rb, rc, rd);
        float p2 = pdot(t20, t21, t22, t23, ra, rb, rc, rd);
        float p3 = pdot(t30, t31, t32, t33, ra, rb, rc, rd);
        float v = xpose_reduce4(p0, p1, p2, p3, tx);
        v = ok ? v : 0.f;
        int j = u - 2 * tx;
        if ((i < 13) && ((unsigned)j < 13u)) ccf[tx * 169 + i * 13 + j] = v;
      }
    }
    __syncthreads();
    // ph7: wave w -> pixel w: gaussian softmax + grid + histogram
    {
      int px = x0 + 2 * w;
      int pix = y * 64 + px;
      float sc[3];
      float lmax = -3e38f;
#pragma unroll
      for (int it = 0; it < 3; ++it) {
        int o = lane + it * 64;
        float scv = -3e38f;
        if (o < 169) {
          int i = o / 13, j = o - i * 13;
          float di = (float)((i - 6) * (i - 6) + (j - 6) * (j - 6));
          scv = 50.f * __expf(-0.5f * di) * ccf[w * 169 + o];
        }
        sc[it] = scv;
        lmax = fmaxf(lmax, scv);
      }
#pragma unroll
      for (int o = 32; o; o >>= 1) lmax = fmaxf(lmax, __shfl_down(lmax, o));
      float m = __shfl(lmax, 0);
      float ee[3];
      float s = 0.f, gx = 0.f, gy = 0.f;
#pragma unroll
      for (int it = 0; it < 3; ++it) {
        int o = lane + it * 64;
        int i = o / 13, j = o - i * 13;
        float e = __expf(sc[it] - m);
        ee[it] = e;
        int yy = y + i - 6, xx = px + j - 6;
        bool inb = (o < 169) && (unsigned)yy < 64u && (unsigned)xx < 64u;
        float xgv = inb ? (-1.f + (2.f / 63.f) * (float)xx) : 0.f;
        float ygv = inb ? (-1.f + (2.f / 63.f) * (float)yy) : 0.f;
        s += e;
        gx += e * xgv;
        gy += e * ygv;
      }
#pragma unroll
      for (int o = 32; o; o >>= 1) {
        s += __shfl_down(s, o);
        gx += __shfl_down(gx, o);
        gy += __shfl_down(gy, o);
      }
      float S = __shfl(s, 0);
      float invS = 1.f / S;
#pragma unroll
      for (int it = 0; it < 3; ++it) {
        int o = lane + it * 64;
        if (o < 169) {
          int i = o / 13, j = o - i * 13;
          int yy = y + i - 6, xx = px + j - 6;
          if ((unsigned)yy < 64u && (unsigned)xx < 64u)
            atomicAdd(&bins[w][lblp[(k << 12) + yy * 64 + xx]],
                      ee[it] * invS);
        }
      }
      if (lane == 0) {
        grid[(k * NPIX + pix) * 2 + 0] = gx * invS;
        grid[(k * NPIX + pix) * 2 + 1] = gy * invS;
      }
    }
  }
  __syncthreads();

  // ---- out write: 32 ch x 4 px
  if (tid < 128) {
    int p = tid & 3, c = tid >> 2;
    out[c * NPIX + y * 64 + x0 + 2 * p] = bins[p][c];
  }
}

// ---------------------------------------------------------------------------
extern "C" void kernel_launch(void* const* d_in, const int* in_sizes, int n_in,
                              void* d_out, int out_size, void* d_ws,
                              size_t ws_size, hipStream_t stream) {
  const float* fr = (const float*)d_in[0];  // feats_r (3,1,64,64,64)
  const float* ft = (const float*)d_in[1];  // feats_t (1,64,64,64)
  const int* q = (const int*)d_in[2];       // quantized_r (3,1,1,256,256)
  float* out = (float*)d_out;               // 131072 + 24576 floats
  float* grid = out + 32 * NPIX;

  float* ws = (float*)d_ws;
  float* tT = ws;                                        // 4096*64
  float* rT = ws + 262144;                               // 3*4096*64
  unsigned char* lblp = (unsigned char*)(ws + 1048576);  // 3*4096 uchar

  k_transpose<<<dim3(64, 4), 256, 0, stream>>>(ft, fr, q, tT, rT, lblp);
  k_fused<<<dim3(16, 64), 256, 0, stream>>>(tT, rT, lblp, out, grid);
}

// Round 8
// 55.248 us; speedup vs baseline: 6.8577x; 1.0671x over previous
//
#include <hip/hip_runtime.h>

// Problem constants (fixed inputs: ref_index=[0,1,2], current_ind=16)
// -> nsearch=1, dirates=[2], nref=3
// feats_r: (3,1,64,64,64) f32, feats_t: (1,64,64,64) f32,
// quantized_r: (3,1,1,256,256) i32
// out: (1,32,64,64) f32 then grid: (3,64,64,2) f32

#define NPIX 4096   // 64*64

// 16-channel partial dot (this lane's quarter of the 64-ch dot).
__device__ __forceinline__ float pdot(float4 t0, float4 t1, float4 t2,
                                      float4 t3, float4 a, float4 b, float4 c,
                                      float4 d) {
  float s0 = 0.f, s1 = 0.f, s2 = 0.f, s3 = 0.f;
  s0 = fmaf(t0.x, a.x, s0); s1 = fmaf(t0.y, a.y, s1);
  s2 = fmaf(t0.z, a.z, s2); s3 = fmaf(t0.w, a.w, s3);
  s0 = fmaf(t1.x, b.x, s0); s1 = fmaf(t1.y, b.y, s1);
  s2 = fmaf(t1.z, b.z, s2); s3 = fmaf(t1.w, b.w, s3);
  s0 = fmaf(t2.x, c.x, s0); s1 = fmaf(t2.y, c.y, s1);
  s2 = fmaf(t2.z, c.z, s2); s3 = fmaf(t2.w, c.w, s3);
  s0 = fmaf(t3.x, d.x, s0); s1 = fmaf(t3.y, d.y, s1);
  s2 = fmaf(t3.z, d.z, s2); s3 = fmaf(t3.w, d.w, s3);
  return (s0 + s1) + (s2 + s3);
}

// 4-lane transpose-reduce: p0..p3 = this lane's 16-ch partials for pixels
// 0..3; result: lane tx holds the full 64-ch dot of pixel tx.
__device__ __forceinline__ float xpose_reduce4(float p0, float p1, float p2,
                                               float p3, int tx) {
  bool o1 = tx & 1, o2 = tx & 2;
  float x01 = __shfl_xor(o1 ? p0 : p1, 1);
  float x23 = __shfl_xor(o1 ? p2 : p3, 1);
  float sA = (o1 ? p1 : p0) + x01;
  float sB = (o1 ? p3 : p2) + x23;
  float z = __shfl_xor(o2 ? sA : sB, 2);
  return o2 ? (sB + z) : (sA + z);
}

__device__ __forceinline__ float wredmax(float v) {
#pragma unroll
  for (int o = 32; o; o >>= 1) v = fmaxf(v, __shfl_down(v, o));
  return __shfl(v, 0);
}
__device__ __forceinline__ float wredsum(float v) {
#pragma unroll
  for (int o = 32; o; o >>= 1) v += __shfl_down(v, o);
  return __shfl(v, 0);
}

// ---------------------------------------------------------------------------
// K0: transpose [c][pix] -> [pix][c] (float4 both sides via LDS tile) and
// pack the (::4,::4) label planes into dense uchar[3][4096].
__global__ __launch_bounds__(256) void k_transpose(
    const float* __restrict__ ft, const float* __restrict__ fr,
    const int* __restrict__ q, float* __restrict__ tT, float* __restrict__ rT,
    unsigned char* __restrict__ lblp) {
  __shared__ float tile[64][65];
  int img = blockIdx.y;
  int pixBase = blockIdx.x * 64;
  const float* src = (img == 0) ? ft : fr + (img - 1) * (64 * NPIX);
  float* dst = (img == 0) ? tT : rT + (img - 1) * (64 * NPIX);
  int tid = threadIdx.x;
#pragma unroll
  for (int it = 0; it < 4; ++it) {
    int idx = it * 256 + tid;
    int c = idx >> 4;
    int p4 = (idx & 15) << 2;
    float4 v = *(const float4*)&src[c * NPIX + pixBase + p4];
    tile[p4 + 0][c] = v.x;
    tile[p4 + 1][c] = v.y;
    tile[p4 + 2][c] = v.z;
    tile[p4 + 3][c] = v.w;
  }
  __syncthreads();
#pragma unroll
  for (int it = 0; it < 4; ++it) {
    int idx = it * 256 + tid;
    int p = idx >> 4;
    int c4 = (idx & 15) << 2;
    float4 v = make_float4(tile[p][c4], tile[p][c4 + 1], tile[p][c4 + 2],
                           tile[p][c4 + 3]);
    *(float4*)&dst[(pixBase + p) * 64 + c4] = v;
  }
  if (img >= 1 && tid < 64) {
    int pix = pixBase + tid;
    lblp[(img - 1) * 4096 + pix] = (unsigned char)
        q[(img - 1) * 65536 + (pix >> 6) * 1024 + (pix & 63) * 4];
  }
}

// ---------------------------------------------------------------------------
// K1: fully fused, 512 threads (8 waves), 4 stride-2 pixels per block.
// t-vectors live in LDS (broadcast reads) to keep VGPR <= 64.
__global__ __launch_bounds__(512) void k_fused(
    const float* __restrict__ tT, const float* __restrict__ rT,
    const unsigned char* __restrict__ lblp, float* __restrict__ out,
    float* __restrict__ grid) {
  int xg = blockIdx.x, y = blockIdx.y;
  int x0 = (xg >> 1) * 8 + (xg & 1);  // pixels x0 + {0,2,4,6}
  int tid = threadIdx.x;
  int gg = tid >> 2, tx = tid & 3;    // 128 groups of 4 lanes
  int w = tid >> 6, lane = tid & 63;  // 8 waves
  int p = w & 3, h = w >> 2;          // wave-pair: pixel p, half h

  __shared__ __align__(16) float tlds[4][64];  // t-vectors, 1 KB
  __shared__ float ccf[2500];                  // 10 KB, phase-reused
  __shared__ float offs[4][2];
  __shared__ float bins[4][33];
  __shared__ float wred[8][4];

  if (tid < 132) ((float*)bins)[tid] = 0.f;
  if (tid < 64) {
    int pp = tid >> 4, c4 = tid & 15;
    ((float4*)&tlds[pp][0])[c4] =
        ((const float4*)&tT[((y << 6) + x0 + 2 * pp) << 6])[c4];
  }
  __syncthreads();

  const float4* TL0 = (const float4*)&tlds[0][0];
  const float4* TL1 = (const float4*)&tlds[1][0];
  const float4* TL2 = (const float4*)&tlds[2][0];
  const float4* TL3 = (const float4*)&tlds[3][0];

  // ---- ph1: 25x32-padded union dilated dots -> ccf[px*625 + oy*25+ox]
  {
    int u = gg & 31;
    int rx = x0 - 24 + 2 * u;
    bool col_ok = ((unsigned)rx < 64u) & (u < 28);
    int colB = min(max(rx, 0), 63) * 64 + tx * 4;
    int ox = u - tx;
    bool st_col = (unsigned)ox < 25u;
    int oyb = gg >> 5;  // 0..3
#pragma unroll 1
    for (int r = 0; r < 7; ++r) {
      int oy = oyb + 4 * r;
      int ry = y + 2 * oy - 24;
      bool ok = col_ok & (oy < 25) & ((unsigned)ry < 64u);
      const float4* rp = (const float4*)&rT[min(max(ry, 0), 63) * 4096 + colB];
      float4 ra = rp[0], rb = rp[4], rc = rp[8], rd = rp[12];
      float p0 = pdot(TL0[tx], TL0[tx + 4], TL0[tx + 8], TL0[tx + 12], ra, rb, rc, rd);
      float p1 = pdot(TL1[tx], TL1[tx + 4], TL1[tx + 8], TL1[tx + 12], ra, rb, rc, rd);
      float p2 = pdot(TL2[tx], TL2[tx + 4], TL2[tx + 8], TL2[tx + 12], ra, rb, rc, rd);
      float p3 = pdot(TL3[tx], TL3[tx + 4], TL3[tx + 8], TL3[tx + 12], ra, rb, rc, rd);
      float v = xpose_reduce4(p0, p1, p2, p3, tx);
      v = ok ? v : 0.f;
      if (st_col && (oy < 25)) ccf[tx * 625 + oy * 25 + ox] = v;
    }
  }
  __syncthreads();

  // ---- ph2: offset softmax-expectation, 2 waves per pixel + LDS combine
  {
    float vv[5];
    float m = -3e38f;
#pragma unroll
    for (int it = 0; it < 5; ++it) {
      int o = lane + (h << 6) + (it << 7);
      float v = (o < 625) ? ccf[p * 625 + o] : -3e38f;
      vv[it] = v;
      m = fmaxf(m, v);
    }
    m = wredmax(m);
    float s = 0.f, sx = 0.f, sy = 0.f;
#pragma unroll
    for (int it = 0; it < 5; ++it) {
      int o = lane + (h << 6) + (it << 7);
      int oy = o / 25, ox = o - oy * 25;
      float e = __expf(vv[it] - m);  // invalid: 0
      s += e;
      sx += e * (float)(ox - 12);
      sy += e * (float)(oy - 12);
    }
    s = wredsum(s); sx = wredsum(sx); sy = wredsum(sy);
    if (lane == 0) {
      wred[w][0] = m; wred[w][1] = s; wred[w][2] = sx; wred[w][3] = sy;
    }
    __syncthreads();
    if (h == 0 && lane == 0) {
      float m2 = wred[w + 4][0], s2 = wred[w + 4][1];
      float sx2 = wred[w + 4][2], sy2 = wred[w + 4][3];
      float M = fmaxf(m, m2);
      float f1 = __expf(m - M), f2 = __expf(m2 - M);
      float S = s * f1 + s2 * f2;
      offs[p][0] = 2.f * (sx * f1 + sx2 * f2) / S;
      offs[p][1] = 2.f * (sy * f1 + sy2 * f2) / S;
    }
  }
  __syncthreads();

  // ---- ph3: deformed 14x14 dot grids, 32 groups (2 waves) per pixel
  {
    int pp = gg >> 5;
    float offx = offs[pp][0], offy = offs[pp][1];
    int iy0 = y + (int)floorf(offy) - 6;
    int ix0 = x0 + 2 * pp + (int)floorf(offx) - 6;
    const float4* TL = (const float4*)&tlds[pp][0];
    float4 T0 = TL[tx], T1 = TL[tx + 4], T2 = TL[tx + 8], T3 = TL[tx + 12];
    int ib = gg & 31;
#pragma unroll 1
    for (int r = 0; r < 7; ++r) {
      int idx = ib + (r << 5);          // 0..223
      int a = idx / 14, b = idx - a * 14;
      int ry = iy0 + a, rx = ix0 + b;
      bool ok = (idx < 196) & ((unsigned)ry < 64u) & ((unsigned)rx < 64u);
      const float4* rp = (const float4*)
          &rT[(min(max(ry, 0), 63) * 64 + min(max(rx, 0), 63)) * 64];
      float4 ra = rp[tx], rb = rp[tx + 4], rc = rp[tx + 8], rd = rp[tx + 12];
      float v = pdot(T0, T1, T2, T3, ra, rb, rc, rd);
      v += __shfl_xor(v, 1);
      v += __shfl_xor(v, 2);
      v = ok ? v : 0.f;
      if ((idx < 196) && tx == 0) ccf[pp * 196 + idx] = v;
    }
  }
  __syncthreads();

  // ---- ph4: ref0 bilinear-combine gaussian softmax (2 waves/pixel)
  {
    int px = x0 + 2 * p;
    int pix = y * 64 + px;
    float offx = offs[p][0], offy = offs[p][1];
    float fy = floorf(offy), fx = floorf(offx);
    float wy = offy - fy, wx = offx - fx;
    float w00 = (1.f - wy) * (1.f - wx), w01 = (1.f - wy) * wx;
    float w10 = wy * (1.f - wx), w11 = wy * wx;
    const float* Dw = &ccf[p * 196];
    float sc[2];
    float m = -3e38f;
#pragma unroll
    for (int it = 0; it < 2; ++it) {
      int o = lane + (h << 6) + (it << 7);
      float scv = -3e38f;
      if (o < 169) {
        int i = o / 13, j = o - i * 13;
        float v = w00 * Dw[i * 14 + j] + w01 * Dw[i * 14 + j + 1] +
                  w10 * Dw[(i + 1) * 14 + j] + w11 * Dw[(i + 1) * 14 + j + 1];
        float di = (float)((i - 6) * (i - 6) + (j - 6) * (j - 6));
        scv = 50.f * __expf(-0.5f * di) * v;
      }
      sc[it] = scv;
      m = fmaxf(m, scv);
    }
    m = wredmax(m);
    float ee[2];
    float s = 0.f, gx = 0.f, gy = 0.f;
#pragma unroll
    for (int it = 0; it < 2; ++it) {
      int o = lane + (h << 6) + (it << 7);
      int i = o / 13, j = o - i * 13;
      float e = __expf(sc[it] - m);
      ee[it] = e;
      int yy = y + i - 6, xx = px + j - 6;
      bool inb = (o < 169) && (unsigned)yy < 64u && (unsigned)xx < 64u;
      float xgv = inb ? (-1.f + (2.f / 63.f) * (float)xx) : 0.f;
      float ygv = inb ? (-1.f + (2.f / 63.f) * (float)yy) : 0.f;
      s += e;
      gx += e * xgv;
      gy += e * ygv;
    }
    s = wredsum(s); gx = wredsum(gx); gy = wredsum(gy);
    if (lane == 0) {
      wred[w][0] = m; wred[w][1] = s; wred[w][2] = gx; wred[w][3] = gy;
    }
    __syncthreads();
    float mo = wred[w ^ 4][0], so = wred[w ^ 4][1];
    float gxo = wred[w ^ 4][2], gyo = wred[w ^ 4][3];
    float M = fmaxf(m, mo);
    float fs = __expf(m - M), fo = __expf(mo - M);
    float invS = 1.f / (s * fs + so * fo);
#pragma unroll
    for (int it = 0; it < 2; ++it) {
      int o = lane + (h << 6) + (it << 7);
      if (o < 169) ccf[1024 + p * 169 + o] = ee[it] * fs * invS;
    }
    if (h == 0 && lane == 0) {
      grid[pix * 2 + 0] = (gx * fs + gxo * fo) * invS;
      grid[pix * 2 + 1] = (gy * fs + gyo * fo) * invS;
    }
  }
  __syncthreads();

  // ---- ph5: ref0 inverse-bilinear histogram (2 waves/pixel)
  {
    float offx = offs[p][0], offy = offs[p][1];
    float fy = floorf(offy), fx = floorf(offx);
    float wy = offy - fy, wx = offx - fx;
    float w00 = (1.f - wy) * (1.f - wx), w01 = (1.f - wy) * wx;
    float w10 = wy * (1.f - wx), w11 = wy * wx;
    int by = y + (int)fy - 6, bx = x0 + 2 * p + (int)fx - 6;
    const float* crp = &ccf[1024 + p * 169];
#pragma unroll
    for (int it = 0; it < 2; ++it) {
      int idx = lane + (h << 6) + (it << 7);
      if (idx < 196) {
        int a = idx / 14, b = idx - a * 14;
        int ry = by + a, rx = bx + b;
        if ((unsigned)ry < 64u && (unsigned)rx < 64u) {
          float wgt = 0.f;
          if (a < 13) {
            if (b < 13) wgt = fmaf(w00, crp[a * 13 + b], wgt);
            if (b > 0) wgt = fmaf(w01, crp[a * 13 + b - 1], wgt);
          }
          if (a > 0) {
            if (b < 13) wgt = fmaf(w10, crp[(a - 1) * 13 + b], wgt);
            if (b > 0) wgt = fmaf(w11, crp[(a - 1) * 13 + b - 1], wgt);
          }
          if (wgt != 0.f) atomicAdd(&bins[p][lblp[ry * 64 + rx]], wgt);
        }
      }
    }
  }
  // no barrier needed: next phase writes ccf[0..676), ph5 reads ccf[1024+)

  // ---- refs 1,2: union dots -> split softmax -> grid + histogram
#pragma unroll 1
  for (int k = 1; k <= 2; ++k) {
    const float* rb0 = rT + k * (64 * NPIX);
    // ph6: 13x19 union, 2 rounds of 128 groups -> ccf[px*169 + i*13+j]
    {
#pragma unroll 1
      for (int r = 0; r < 2; ++r) {
        int tu = gg + (r << 7);
        int i = tu / 19, u = tu - i * 19;
        int ry = y + i - 6, rx = x0 - 6 + u;
        bool ok = (i < 13) & ((unsigned)ry < 64u) & ((unsigned)rx < 64u);
        const float4* rp = (const float4*)
            &rb0[(min(max(ry, 0), 63) * 64 + min(max(rx, 0), 63)) * 64];
        float4 ra = rp[tx], rb = rp[tx + 4], rc = rp[tx + 8], rd = rp[tx + 12];
        float p0 = pdot(TL0[tx], TL0[tx + 4], TL0[tx + 8], TL0[tx + 12], ra, rb, rc, rd);
        float p1 = pdot(TL1[tx], TL1[tx + 4], TL1[tx + 8], TL1[tx + 12], ra, rb, rc, rd);
        float p2 = pdot(TL2[tx], TL2[tx + 4], TL2[tx + 8], TL2[tx + 12], ra, rb, rc, rd);
        float p3 = pdot(TL3[tx], TL3[tx + 4], TL3[tx + 8], TL3[tx + 12], ra, rb, rc, rd);
        float v = xpose_reduce4(p0, p1, p2, p3, tx);
        v = ok ? v : 0.f;
        int j = u - 2 * tx;
        if ((i < 13) && ((unsigned)j < 13u)) ccf[tx * 169 + i * 13 + j] = v;
      }
    }
    __syncthreads();
    // ph7: gaussian softmax + grid + histogram (2 waves/pixel)
    {
      int px = x0 + 2 * p;
      int pix = y * 64 + px;
      float sc[2];
      float m = -3e38f;
#pragma unroll
      for (int it = 0; it < 2; ++it) {
        int o = lane + (h << 6) + (it << 7);
        float scv = -3e38f;
        if (o < 169) {
          int i = o / 13, j = o - i * 13;
          float di = (float)((i - 6) * (i - 6) + (j - 6) * (j - 6));
          scv = 50.f * __expf(-0.5f * di) * ccf[p * 169 + o];
        }
        sc[it] = scv;
        m = fmaxf(m, scv);
      }
      m = wredmax(m);
      float ee[2];
      float s = 0.f, gx = 0.f, gy = 0.f;
#pragma unroll
      for (int it = 0; it < 2; ++it) {
        int o = lane + (h << 6) + (it << 7);
        int i = o / 13, j = o - i * 13;
        float e = __expf(sc[it] - m);
        ee[it] = e;
        int yy = y + i - 6, xx = px + j - 6;
        bool inb = (o < 169) && (unsigned)yy < 64u && (unsigned)xx < 64u;
        float xgv = inb ? (-1.f + (2.f / 63.f) * (float)xx) : 0.f;
        float ygv = inb ? (-1.f + (2.f / 63.f) * (float)yy) : 0.f;
        s += e;
        gx += e * xgv;
        gy += e * ygv;
      }
      s = wredsum(s); gx = wredsum(gx); gy = wredsum(gy);
      if (lane == 0) {
        wred[w][0] = m; wred[w][1] = s; wred[w][2] = gx; wred[w][3] = gy;
      }
      __syncthreads();
      float mo = wred[w ^ 4][0], so = wred[w ^ 4][1];
      float gxo = wred[w ^ 4][2], gyo = wred[w ^ 4][3];
      float M = fmaxf(m, mo);
      float fs = __expf(m - M), fo = __expf(mo - M);
      float invS = 1.f / (s * fs + so * fo);
#pragma unroll
      for (int it = 0; it < 2; ++it) {
        int o = lane + (h << 6) + (it << 7);
        if (o < 169) {
          int i = o / 13, j = o - i * 13;
          int yy = y + i - 6, xx = px + j - 6;
          if ((unsigned)yy < 64u && (unsigned)xx < 64u)
            atomicAdd(&bins[p][lblp[(k << 12) + yy * 64 + xx]],
                      ee[it] * fs * invS);
        }
      }
      if (h == 0 && lane == 0) {
        grid[(k * NPIX + pix) * 2 + 0] = (gx * fs + gxo * fo) * invS;
        grid[(k * NPIX + pix) * 2 + 1] = (gy * fs + gyo * fo) * invS;
      }
    }
  }
  __syncthreads();

  // ---- out write: 32 ch x 4 px
  if (tid < 128) {
    int pp = tid & 3, c = tid >> 2;
    out[c * NPIX + y * 64 + x0 + 2 * pp] = bins[pp][c];
  }
}

// ---------------------------------------------------------------------------
extern "C" void kernel_launch(void* const* d_in, const int* in_sizes, int n_in,
                              void* d_out, int out_size, void* d_ws,
                              size_t ws_size, hipStream_t stream) {
  const float* fr = (const float*)d_in[0];  // feats_r (3,1,64,64,64)
  const float* ft = (const float*)d_in[1];  // feats_t (1,64,64,64)
  const int* q = (const int*)d_in[2];       // quantized_r (3,1,1,256,256)
  float* out = (float*)d_out;               // 131072 + 24576 floats
  float* grid = out + 32 * NPIX;

  float* ws = (float*)d_ws;
  float* tT = ws;                                        // 4096*64
  float* rT = ws + 262144;                               // 3*4096*64
  unsigned char* lblp = (unsigned char*)(ws + 1048576);  // 3*4096 uchar

  k_transpose<<<dim3(64, 4), 256, 0, stream>>>(ft, fr, q, tT, rT, lblp);
  k_fused<<<dim3(16, 64), 512, 0, stream>>>(tT, rT, lblp, out, grid);
}